// Round 1
// baseline (5029.968 us; speedup 1.0000x reference)
//
#include <hip/hip_runtime.h>
#include <float.h>

// CloudNet (PointNet++-ish) full pipeline on MI355X.
// Correctness contract: FPS + radius selection must be bit-exact vs numpy f32
// (no FMA contraction -> explicit __f*_rn ops; argmax/top_k tie-breaks by
// lowest index). MLP math is plain f32 (tolerance absorbs rounding).

__device__ __forceinline__ float d2_rn(float ax, float ay, float az,
                                       float bx, float by, float bz) {
  float dx = __fsub_rn(ax, bx), dy = __fsub_rn(ay, by), dz = __fsub_rn(az, bz);
  return __fadd_rn(__fadd_rn(__fmul_rn(dx, dx), __fmul_rn(dy, dy)), __fmul_rn(dz, dz));
}

// ---------------- FPS: one block per cloud, sequential argmax loop ----------
template<int N, int NS>
__global__ __launch_bounds__(256) void fps_kernel(const float* __restrict__ pos,
                                                  float* __restrict__ posq) {
  constexpr int T = 256;
  constexpr int P = N / T;
  __shared__ float s_pos[N * 3];
  __shared__ int   s_idx[NS];
  __shared__ float s_v[2][4];
  __shared__ int   s_i[2][4];
  const int t = threadIdx.x, b = blockIdx.x;
  const float* pb = pos + (size_t)b * N * 3;
  for (int i = t; i < N * 3; i += T) s_pos[i] = pb[i];
  __syncthreads();
  float px[P], py[P], pz[P], mind[P];
#pragma unroll
  for (int j = 0; j < P; ++j) {
    const int i = j * T + t;
    px[j] = s_pos[i*3]; py[j] = s_pos[i*3+1]; pz[j] = s_pos[i*3+2];
    mind[j] = FLT_MAX;   // ref inits to finfo(f32).max
  }
  if (t == 0) s_idx[0] = 0;      // deterministic start at point 0
  float lx = s_pos[0], ly = s_pos[1], lz = s_pos[2];
  for (int it = 1; it < NS; ++it) {
    float bv = -1.0f; int bi = 0;
#pragma unroll
    for (int j = 0; j < P; ++j) {
      const float d = d2_rn(px[j], py[j], pz[j], lx, ly, lz);
      const float m = fminf(mind[j], d);
      mind[j] = m;
      if (m > bv) { bv = m; bi = j * T + t; }   // strict > => first index wins
    }
#pragma unroll
    for (int off = 32; off > 0; off >>= 1) {
      const float ov = __shfl_down(bv, off, 64);
      const int   oi = __shfl_down(bi, off, 64);
      if (ov > bv || (ov == bv && oi < bi)) { bv = ov; bi = oi; }
    }
    const int par = it & 1, w = t >> 6;
    if ((t & 63) == 0) { s_v[par][w] = bv; s_i[par][w] = bi; }
    __syncthreads();
    bv = s_v[par][0]; bi = s_i[par][0];
#pragma unroll
    for (int k = 1; k < 4; ++k) {
      const float ov = s_v[par][k]; const int oi = s_i[par][k];
      if (ov > bv || (ov == bv && oi < bi)) { bv = ov; bi = oi; }
    }
    if (t == 0) s_idx[it] = bi;
    lx = s_pos[bi*3]; ly = s_pos[bi*3+1]; lz = s_pos[bi*3+2];
  }
  __syncthreads();
  for (int s = t; s < NS; s += T) {
    const int i = s_idx[s];
    posq[((size_t)b*NS + s)*3 + 0] = s_pos[i*3 + 0];
    posq[((size_t)b*NS + s)*3 + 1] = s_pos[i*3 + 1];
    posq[((size_t)b*NS + s)*3 + 2] = s_pos[i*3 + 2];
  }
}

// ------------- radius-NN: one block per query, rank-select top-64 -----------
template<int CAP>
__global__ __launch_bounds__(128) void radius_kernel(
    const float* __restrict__ pall, const float* __restrict__ pq,
    int N, int M, float r2,
    int* __restrict__ nidx, int* __restrict__ ncnt) {
  const int bm = blockIdx.x;
  const int b = bm / M;
  const int t = threadIdx.x;
  __shared__ float s_d2[CAP];
  __shared__ int   s_id[CAP];
  __shared__ int   s_cnt;
  if (t == 0) s_cnt = 0;
  __syncthreads();
  const float* pb = pall + (size_t)b * N * 3;
  const float qx = pq[(size_t)bm*3], qy = pq[(size_t)bm*3+1], qz = pq[(size_t)bm*3+2];
  for (int i = t; i < N; i += 128) {
    const float d2 = d2_rn(qx, qy, qz, pb[i*3], pb[i*3+1], pb[i*3+2]);
    if (d2 <= r2) {
      const int p = atomicAdd(&s_cnt, 1);
      if (p < CAP) { s_d2[p] = d2; s_id[p] = i; }
    }
  }
  __syncthreads();
  const int cnt = min(s_cnt, CAP);
  int* out = nidx + (size_t)bm * 64;
  if (cnt <= 64) {
    if (t < cnt) out[t] = s_id[t];      // set equality suffices (max-agg)
    if (t == 0) ncnt[bm] = cnt;
  } else {
    // top_k(-d2): smallest d2, ties -> lower index. (d2,idx) lex rank < 64.
    for (int c = t; c < cnt; c += 128) {
      const float dc = s_d2[c]; const int ic = s_id[c];
      int rank = 0;
      for (int jj = 0; jj < cnt; ++jj)
        rank += (s_d2[jj] < dc) || (s_d2[jj] == dc && s_id[jj] < ic);
      if (rank < 64) out[rank] = s_id[c];
    }
    if (t == 0) ncnt[bm] = 64;
  }
}

// --------- conv1: msg=rel(3) -> 64 -> 64 -> 128, masked max, relu -----------
__global__ __launch_bounds__(64) void conv1_kernel(
    const float* __restrict__ pos, const float* __restrict__ posq,
    const int* __restrict__ nidx, const int* __restrict__ ncnt,
    const float* __restrict__ w1, const float* __restrict__ b1,
    const float* __restrict__ w2, const float* __restrict__ b2,
    const float* __restrict__ w3, const float* __restrict__ b3,
    float* __restrict__ xout) {
  const int bm = blockIdx.x;      // b*2048 + m
  const int b  = bm >> 11;
  const int j  = threadIdx.x;     // lane = neighbor row
  __shared__ float s_h[64 * 65];  // stride 65: conflict-free own-row access
  const int cnt = ncnt[bm];
  float* outp = xout + (size_t)bm * 128;
  if (cnt == 0) { outp[j] = 0.f; outp[j + 64] = 0.f; return; }
  const float qx = posq[(size_t)bm*3+0], qy = posq[(size_t)bm*3+1], qz = posq[(size_t)bm*3+2];
  const bool act = j < cnt;
  float rx = 0.f, ry = 0.f, rz = 0.f;
  if (act) {
    const int n = nidx[(size_t)bm*64 + j];
    const float* p = pos + ((size_t)b*4096 + n) * 3;
    rx = p[0] - qx; ry = p[1] - qy; rz = p[2] - qz;
  }
  // L1: 3->64 + relu
#pragma unroll
  for (int c = 0; c < 64; ++c) {
    const float a = b1[c] + rx * w1[c] + ry * w1[64 + c] + rz * w1[128 + c];
    s_h[j*65 + c] = fmaxf(a, 0.f);
  }
  __syncthreads();
  // L2: 64->64 + relu (weights wave-uniform -> scalar loads)
  float acc[64];
#pragma unroll
  for (int c = 0; c < 64; ++c) acc[c] = b2[c];
#pragma unroll 1
  for (int k = 0; k < 64; ++k) {
    const float hk = s_h[j*65 + k];
#pragma unroll
    for (int c4 = 0; c4 < 16; ++c4) {
      const float4 w = *(const float4*)(w2 + k*64 + c4*4);
      acc[c4*4+0] += hk * w.x; acc[c4*4+1] += hk * w.y;
      acc[c4*4+2] += hk * w.z; acc[c4*4+3] += hk * w.w;
    }
  }
  __syncthreads();
#pragma unroll
  for (int c = 0; c < 64; ++c) s_h[j*65 + c] = fmaxf(acc[c], 0.f);
  __syncthreads();
  // L3: 64->128 + masked col-max over rows + outer relu
#pragma unroll 1
  for (int ch = 0; ch < 2; ++ch) {
    float a3[64];
#pragma unroll
    for (int c = 0; c < 64; ++c) a3[c] = b3[ch*64 + c];
#pragma unroll 1
    for (int k = 0; k < 64; ++k) {
      const float hk = s_h[j*65 + k];
#pragma unroll
      for (int c4 = 0; c4 < 16; ++c4) {
        const float4 w = *(const float4*)(w3 + k*128 + ch*64 + c4*4);
        a3[c4*4+0] += hk * w.x; a3[c4*4+1] += hk * w.y;
        a3[c4*4+2] += hk * w.z; a3[c4*4+3] += hk * w.w;
      }
    }
    float res = 0.f;
#pragma unroll
    for (int c = 0; c < 64; ++c) {
      float v = act ? a3[c] : -1e30f;   // matches ref NEG masking
#pragma unroll
      for (int off = 32; off > 0; off >>= 1) v = fmaxf(v, __shfl_xor(v, off, 64));
      if (j == c) res = v;
    }
    outp[ch*64 + j] = fmaxf(res, 0.f);
  }
}

// --- conv2: msg=[x1_j(128), rel(3)] -> 128 -> 128 -> 256, masked max, relu --
__global__ __launch_bounds__(64) void conv2_kernel(
    const float* __restrict__ x1, const float* __restrict__ pos1, const float* __restrict__ pos2,
    const int* __restrict__ nidx, const int* __restrict__ ncnt,
    const float* __restrict__ w1, const float* __restrict__ b1,
    const float* __restrict__ w2, const float* __restrict__ b2,
    const float* __restrict__ w3, const float* __restrict__ b3,
    float* __restrict__ xout) {
  const int bm = blockIdx.x;      // b*512 + m
  const int b  = bm >> 9;
  const int j  = threadIdx.x;
  __shared__ float s_h[64 * 128]; // XOR-swizzled rows (conflict-free col reads)
  const int cnt = ncnt[bm];
  float* outp = xout + (size_t)bm * 256;
  if (cnt == 0) {
#pragma unroll
    for (int c = 0; c < 4; ++c) outp[c*64 + j] = 0.f;
    return;
  }
  const float qx = pos2[(size_t)bm*3+0], qy = pos2[(size_t)bm*3+1], qz = pos2[(size_t)bm*3+2];
  const bool act = j < cnt;
  int n = 0;
  float rx = 0.f, ry = 0.f, rz = 0.f;
  if (act) {
    n = nidx[(size_t)bm*64 + j];
    const float* p = pos1 + ((size_t)b*2048 + n) * 3;
    rx = p[0] - qx; ry = p[1] - qy; rz = p[2] - qz;
  }
  const float* xj = x1 + ((size_t)b*2048 + n) * 128;  // n=0 for idle lanes: finite garbage, masked later
  const int sw = (j & 31);
  float acc[128];
#pragma unroll
  for (int c = 0; c < 128; ++c) acc[c] = b1[c];
  auto fmarow1 = [&](int krow, float xk) {
#pragma unroll
    for (int c4 = 0; c4 < 32; ++c4) {
      const float4 w = *(const float4*)(w1 + krow*128 + c4*4);
      acc[c4*4+0] += xk*w.x; acc[c4*4+1] += xk*w.y;
      acc[c4*4+2] += xk*w.z; acc[c4*4+3] += xk*w.w;
    }
  };
#pragma unroll 1
  for (int k = 0; k < 128; k += 4) {
    const float4 xv = *(const float4*)(xj + k);
    fmarow1(k+0, xv.x); fmarow1(k+1, xv.y); fmarow1(k+2, xv.z); fmarow1(k+3, xv.w);
  }
  fmarow1(128, rx); fmarow1(129, ry); fmarow1(130, rz);
#pragma unroll
  for (int c = 0; c < 128; ++c) s_h[j*128 + (c ^ sw)] = fmaxf(acc[c], 0.f);
  __syncthreads();
  // L2: 128->128 + relu
  float a2[128];
#pragma unroll
  for (int c = 0; c < 128; ++c) a2[c] = b2[c];
#pragma unroll 1
  for (int k = 0; k < 128; ++k) {
    const float hk = s_h[j*128 + (k ^ sw)];
#pragma unroll
    for (int c4 = 0; c4 < 32; ++c4) {
      const float4 w = *(const float4*)(w2 + k*128 + c4*4);
      a2[c4*4+0] += hk*w.x; a2[c4*4+1] += hk*w.y;
      a2[c4*4+2] += hk*w.z; a2[c4*4+3] += hk*w.w;
    }
  }
  __syncthreads();
#pragma unroll
  for (int c = 0; c < 128; ++c) s_h[j*128 + (c ^ sw)] = fmaxf(a2[c], 0.f);
  __syncthreads();
  // L3: 128->256 + masked col-max + relu
#pragma unroll 1
  for (int ch = 0; ch < 4; ++ch) {
    float a3[64];
#pragma unroll
    for (int c = 0; c < 64; ++c) a3[c] = b3[ch*64 + c];
#pragma unroll 1
    for (int k = 0; k < 128; ++k) {
      const float hk = s_h[j*128 + (k ^ sw)];
#pragma unroll
      for (int c4 = 0; c4 < 16; ++c4) {
        const float4 w = *(const float4*)(w3 + k*256 + ch*64 + c4*4);
        a3[c4*4+0] += hk*w.x; a3[c4*4+1] += hk*w.y;
        a3[c4*4+2] += hk*w.z; a3[c4*4+3] += hk*w.w;
      }
    }
    float res = 0.f;
#pragma unroll
    for (int c = 0; c < 64; ++c) {
      float v = act ? a3[c] : -1e30f;
#pragma unroll
      for (int off = 32; off > 0; off >>= 1) v = fmaxf(v, __shfl_xor(v, off, 64));
      if (j == c) res = v;
    }
    outp[ch*64 + j] = fmaxf(res, 0.f);
  }
}

// --------- global MLP 259->256->512->1024, per-block(16pt) partial max ------
__global__ __launch_bounds__(256) void gmlp_kernel(
    const float* __restrict__ x2, const float* __restrict__ pos2,
    const float* __restrict__ w1, const float* __restrict__ b1,
    const float* __restrict__ w2, const float* __restrict__ b2,
    const float* __restrict__ w3, const float* __restrict__ b3,
    float* __restrict__ gpart) {
  const int blk = blockIdx.x;     // 16 points per block (group = 8 blocks)
  const int t = threadIdx.x;
  __shared__ float sA[16 * 260];  // input, reused for H1
  __shared__ float sB[16 * 512];  // H2
  const int p0 = blk * 16;
  for (int i = t; i < 16*256; i += 256) {
    const int p = i >> 8, k = i & 255;
    sA[p*260 + k] = x2[(size_t)(p0 + p)*256 + k];
  }
  if (t < 48) { const int p = t/3, c = t%3; sA[p*260 + 256 + c] = pos2[(size_t)(p0+p)*3 + c]; }
  __syncthreads();
  float h1[16];
#pragma unroll
  for (int p = 0; p < 16; ++p) h1[p] = b1[t];
#pragma unroll 1
  for (int k = 0; k < 259; ++k) {
    const float w = w1[(size_t)k*256 + t];
#pragma unroll
    for (int p = 0; p < 16; ++p) h1[p] += sA[p*260 + k] * w;
  }
  __syncthreads();
#pragma unroll
  for (int p = 0; p < 16; ++p) sA[p*260 + t] = fmaxf(h1[p], 0.f);
  __syncthreads();
  float h2a[16], h2b[16];
#pragma unroll
  for (int p = 0; p < 16; ++p) { h2a[p] = b2[t]; h2b[p] = b2[t + 256]; }
#pragma unroll 1
  for (int k = 0; k < 256; ++k) {
    const float wa = w2[(size_t)k*512 + t];
    const float wb = w2[(size_t)k*512 + t + 256];
#pragma unroll
    for (int p = 0; p < 16; ++p) { const float x = sA[p*260 + k]; h2a[p] += x*wa; h2b[p] += x*wb; }
  }
#pragma unroll
  for (int p = 0; p < 16; ++p) { sB[p*512 + t] = fmaxf(h2a[p], 0.f); sB[p*512 + t + 256] = fmaxf(h2b[p], 0.f); }
  __syncthreads();
  float a3[4][16];
#pragma unroll
  for (int c = 0; c < 4; ++c) {
    const float bb = b3[t + c*256];
#pragma unroll
    for (int p = 0; p < 16; ++p) a3[c][p] = bb;
  }
#pragma unroll 1
  for (int k = 0; k < 512; ++k) {
    float hk[16];
#pragma unroll
    for (int p = 0; p < 16; ++p) hk[p] = sB[p*512 + k];
#pragma unroll
    for (int c = 0; c < 4; ++c) {
      const float w = w3[(size_t)k*1024 + t + c*256];
#pragma unroll
      for (int p = 0; p < 16; ++p) a3[c][p] += hk[p] * w;
    }
  }
#pragma unroll
  for (int c = 0; c < 4; ++c) {
    float m = a3[c][0];
#pragma unroll
    for (int p = 1; p < 16; ++p) m = fmaxf(m, a3[c][p]);
    gpart[(size_t)blk*1024 + t + c*256] = m;
  }
}

__global__ __launch_bounds__(256) void gmax_kernel(const float* __restrict__ gpart,
                                                   float* __restrict__ gmaxb) {
  const int g = blockIdx.x >> 2, chunk = blockIdx.x & 3;
  const int ch = chunk*256 + threadIdx.x;
  float v = gpart[(size_t)(g*8)*1024 + ch];
#pragma unroll
  for (int r = 1; r < 8; ++r) v = fmaxf(v, gpart[(size_t)(g*8 + r)*1024 + ch]);
  gmaxb[(size_t)g*1024 + ch] = v;
}

// ---------------- head MLP 1024->512->256->7 per group-row ------------------
__global__ __launch_bounds__(256) void head_kernel(
    const float* __restrict__ gin,
    const float* __restrict__ l1w, const float* __restrict__ l1b,
    const float* __restrict__ l2w, const float* __restrict__ l2b,
    const float* __restrict__ l3w, const float* __restrict__ l3b,
    float* __restrict__ h3) {
  const int r = blockIdx.x, t = threadIdx.x;
  __shared__ float sIn[1024];
  __shared__ float sH[512];
  __shared__ float sH2[256];
  for (int i = t; i < 1024; i += 256) sIn[i] = gin[(size_t)r*1024 + i];
  __syncthreads();
  float a0 = l1b[t], a1 = l1b[t + 256];
#pragma unroll 1
  for (int k = 0; k < 1024; ++k) {
    const float x = sIn[k];
    a0 += x * l1w[(size_t)k*512 + t];
    a1 += x * l1w[(size_t)k*512 + t + 256];
  }
  sH[t] = fmaxf(a0, 0.f); sH[t+256] = fmaxf(a1, 0.f);
  __syncthreads();
  float a = l2b[t];
#pragma unroll 1
  for (int k = 0; k < 512; ++k) a += sH[k] * l2w[(size_t)k*256 + t];
  sH2[t] = fmaxf(a, 0.f);
  __syncthreads();
  if (t < 7) {
    float acc = l3b[t];
#pragma unroll 1
    for (int k = 0; k < 256; ++k) acc += sH2[k] * l3w[(size_t)k*7 + t];
    h3[(size_t)r*7 + t] = acc;
  }
}

// ---------------- mean over 4 group-rows + quaternion normalize -------------
__global__ void final_kernel(const float* __restrict__ h3, float* __restrict__ out) {
  const int b = threadIdx.x;
  if (b >= 8) return;
  float v[7];
#pragma unroll
  for (int c = 0; c < 7; ++c) {
    const float s = ((h3[(b*4+0)*7+c] + h3[(b*4+1)*7+c]) + h3[(b*4+2)*7+c]) + h3[(b*4+3)*7+c];
    v[c] = s * 0.25f;
  }
  const float nrm = fmaxf(sqrtf(((v[3]*v[3] + v[4]*v[4]) + v[5]*v[5]) + v[6]*v[6]), 1e-12f);
  out[b*7+0] = v[0]; out[b*7+1] = v[1]; out[b*7+2] = v[2];
  out[b*7+3] = v[3]/nrm; out[b*7+4] = v[4]/nrm;
  out[b*7+5] = v[5]/nrm; out[b*7+6] = v[6]/nrm;
}

extern "C" void kernel_launch(void* const* d_in, const int* in_sizes, int n_in,
                              void* d_out, int out_size, void* d_ws, size_t ws_size,
                              hipStream_t stream) {
  const float* points = (const float*)d_in[0];
  const float* sa1_w1 = (const float*)d_in[1];
  const float* sa1_b1 = (const float*)d_in[2];
  const float* sa1_w2 = (const float*)d_in[3];
  const float* sa1_b2 = (const float*)d_in[4];
  const float* sa1_w3 = (const float*)d_in[5];
  const float* sa1_b3 = (const float*)d_in[6];
  const float* sa2_w1 = (const float*)d_in[7];
  const float* sa2_b1 = (const float*)d_in[8];
  const float* sa2_w2 = (const float*)d_in[9];
  const float* sa2_b2 = (const float*)d_in[10];
  const float* sa2_w3 = (const float*)d_in[11];
  const float* sa2_b3 = (const float*)d_in[12];
  const float* g_w1   = (const float*)d_in[13];
  const float* g_b1   = (const float*)d_in[14];
  const float* g_w2   = (const float*)d_in[15];
  const float* g_b2   = (const float*)d_in[16];
  const float* g_w3   = (const float*)d_in[17];
  const float* g_b3   = (const float*)d_in[18];
  const float* l1_w   = (const float*)d_in[19];
  const float* l1_b   = (const float*)d_in[20];
  const float* l2_w   = (const float*)d_in[21];
  const float* l2_b   = (const float*)d_in[22];
  const float* l3_w   = (const float*)d_in[23];
  const float* l3_b   = (const float*)d_in[24];

  // Workspace carve-up (all 4-byte elements), ~19.3 MB total.
  float* ws = (float*)d_ws;
  size_t o = 0;
  float* pos1  = ws + o; o += (size_t)8*2048*3;
  float* pos2  = ws + o; o += (size_t)8*512*3;
  int*   nidx1 = (int*)(ws + o); o += (size_t)8*2048*64;
  int*   ncnt1 = (int*)(ws + o); o += (size_t)8*2048;
  int*   nidx2 = (int*)(ws + o); o += (size_t)8*512*64;
  int*   ncnt2 = (int*)(ws + o); o += (size_t)8*512;
  float* x1    = ws + o; o += (size_t)8*2048*128;
  float* x2    = ws + o; o += (size_t)8*512*256;
  float* gpart = ws + o; o += (size_t)256*1024;
  float* gmaxb = ws + o; o += (size_t)32*1024;
  float* h3    = ws + o; o += (size_t)32*7;

  // Radius thresholds: Python computes r*r in double, JAX weak-types to f32.
  const float R2_1 = (float)(0.1 * 0.1);
  const float R2_2 = (float)(0.2 * 0.2);

  fps_kernel<4096, 2048><<<8, 256, 0, stream>>>(points, pos1);
  radius_kernel<1024><<<8*2048, 128, 0, stream>>>(points, pos1, 4096, 2048, R2_1, nidx1, ncnt1);
  conv1_kernel<<<8*2048, 64, 0, stream>>>(points, pos1, nidx1, ncnt1,
                                          sa1_w1, sa1_b1, sa1_w2, sa1_b2, sa1_w3, sa1_b3, x1);
  fps_kernel<2048, 512><<<8, 256, 0, stream>>>(pos1, pos2);
  radius_kernel<1024><<<8*512, 128, 0, stream>>>(pos1, pos2, 2048, 512, R2_2, nidx2, ncnt2);
  conv2_kernel<<<8*512, 64, 0, stream>>>(x1, pos1, pos2, nidx2, ncnt2,
                                         sa2_w1, sa2_b1, sa2_w2, sa2_b2, sa2_w3, sa2_b3, x2);
  gmlp_kernel<<<256, 256, 0, stream>>>(x2, pos2, g_w1, g_b1, g_w2, g_b2, g_w3, g_b3, gpart);
  gmax_kernel<<<128, 256, 0, stream>>>(gpart, gmaxb);
  head_kernel<<<32, 256, 0, stream>>>(gmaxb, l1_w, l1_b, l2_w, l2_b, l3_w, l3_b, h3);
  final_kernel<<<1, 64, 0, stream>>>(h3, (float*)d_out);
}

// Round 2
// 4156.906 us; speedup vs baseline: 1.2100x; 1.2100x over previous
//
#include <hip/hip_runtime.h>
#include <float.h>

// CloudNet (PointNet++-ish) full pipeline on MI355X.
// Correctness contract: FPS + radius selection must be bit-exact vs numpy f32
// (no FMA contraction -> explicit __f*_rn ops; argmax/top_k tie-breaks by
// lowest index). MLP math is plain f32 (tolerance absorbs rounding).

__device__ __forceinline__ float d2_rn(float ax, float ay, float az,
                                       float bx, float by, float bz) {
  float dx = __fsub_rn(ax, bx), dy = __fsub_rn(ay, by), dz = __fsub_rn(az, bz);
  return __fadd_rn(__fadd_rn(__fmul_rn(dx, dx), __fmul_rn(dy, dy)), __fmul_rn(dz, dz));
}

// ---------------- FPS v2: one block per cloud, packed-u64 argmax ------------
// Key = (f32_bits(mind) << 32) | (N-1-idx): max-key == argmax with numpy's
// lowest-index tie-break (d2 >= 0 so float bits are order-isomorphic).
template<int N, int NS, int T>
__global__ __launch_bounds__(T) void fps_kernel(const float* __restrict__ pos,
                                                float* __restrict__ posq) {
  constexpr int P = N / T;
  constexpr int W = T / 64;
  __shared__ float sx[N], sy[N], sz[N];
  __shared__ unsigned long long s_red[2][W];
  const int t = threadIdx.x, b = blockIdx.x;
  const float* pb = pos + (size_t)b * N * 3;
  for (int i = t; i < N; i += T) {
    sx[i] = pb[i*3+0]; sy[i] = pb[i*3+1]; sz[i] = pb[i*3+2];
  }
  __syncthreads();
  float px[P], py[P], pz[P], mind[P];
#pragma unroll
  for (int j = 0; j < P; ++j) {
    const int i = j*T + t;
    px[j] = sx[i]; py[j] = sy[i]; pz[j] = sz[i];
    mind[j] = FLT_MAX;   // ref inits to finfo(f32).max
  }
  float lx = sx[0], ly = sy[0], lz = sz[0];   // deterministic start at point 0
  float* outp = posq + (size_t)b * NS * 3;
  if (t == 0) { outp[0] = lx; outp[1] = ly; outp[2] = lz; }
  for (int it = 1; it < NS; ++it) {
    unsigned long long best = 0ull;
#pragma unroll
    for (int j = 0; j < P; ++j) {
      const float dx = __fsub_rn(px[j], lx);
      const float dy = __fsub_rn(py[j], ly);
      const float dz = __fsub_rn(pz[j], lz);
      const float d = __fadd_rn(__fadd_rn(__fmul_rn(dx, dx), __fmul_rn(dy, dy)),
                                __fmul_rn(dz, dz));
      const float m = fminf(mind[j], d);
      mind[j] = m;
      const unsigned long long key =
          ((unsigned long long)__float_as_uint(m) << 32) |
          (unsigned int)(N - 1 - (j*T + t));
      best = key > best ? key : best;
    }
#pragma unroll
    for (int off = 32; off > 0; off >>= 1) {
      const unsigned long long o = __shfl_xor(best, off, 64);
      best = o > best ? o : best;
    }
    if constexpr (W > 1) {
      const int par = it & 1;
      if ((t & 63) == 0) s_red[par][t >> 6] = best;
      __syncthreads();
#pragma unroll
      for (int w = 0; w < W; ++w) {
        const unsigned long long o = s_red[par][w];
        best = o > best ? o : best;
      }
    }
    const int idx = (N - 1) - (int)(unsigned int)(best & 0xFFFFFFFFull);
    lx = sx[idx]; ly = sy[idx]; lz = sz[idx];
    if (t == 0) {   // fire-and-forget; consumed only by later kernels
      outp[(size_t)it*3 + 0] = lx; outp[(size_t)it*3 + 1] = ly; outp[(size_t)it*3 + 2] = lz;
    }
  }
}

// ------------- radius-NN: one block per query, rank-select top-64 -----------
template<int CAP>
__global__ __launch_bounds__(128) void radius_kernel(
    const float* __restrict__ pall, const float* __restrict__ pq,
    int N, int M, float r2,
    int* __restrict__ nidx, int* __restrict__ ncnt) {
  const int bm = blockIdx.x;
  const int b = bm / M;
  const int t = threadIdx.x;
  __shared__ float s_d2[CAP];
  __shared__ int   s_id[CAP];
  __shared__ int   s_cnt;
  if (t == 0) s_cnt = 0;
  __syncthreads();
  const float* pb = pall + (size_t)b * N * 3;
  const float qx = pq[(size_t)bm*3], qy = pq[(size_t)bm*3+1], qz = pq[(size_t)bm*3+2];
  for (int i = t; i < N; i += 128) {
    const float d2 = d2_rn(qx, qy, qz, pb[i*3], pb[i*3+1], pb[i*3+2]);
    if (d2 <= r2) {
      const int p = atomicAdd(&s_cnt, 1);
      if (p < CAP) { s_d2[p] = d2; s_id[p] = i; }
    }
  }
  __syncthreads();
  const int cnt = min(s_cnt, CAP);
  int* out = nidx + (size_t)bm * 64;
  if (cnt <= 64) {
    if (t < cnt) out[t] = s_id[t];      // set equality suffices (max-agg)
    if (t == 0) ncnt[bm] = cnt;
  } else {
    // top_k(-d2): smallest d2, ties -> lower index. (d2,idx) lex rank < 64.
    for (int c = t; c < cnt; c += 128) {
      const float dc = s_d2[c]; const int ic = s_id[c];
      int rank = 0;
      for (int jj = 0; jj < cnt; ++jj)
        rank += (s_d2[jj] < dc) || (s_d2[jj] == dc && s_id[jj] < ic);
      if (rank < 64) out[rank] = s_id[c];
    }
    if (t == 0) ncnt[bm] = 64;
  }
}

// --------- conv1: msg=rel(3) -> 64 -> 64 -> 128, masked max, relu -----------
__global__ __launch_bounds__(64) void conv1_kernel(
    const float* __restrict__ pos, const float* __restrict__ posq,
    const int* __restrict__ nidx, const int* __restrict__ ncnt,
    const float* __restrict__ w1, const float* __restrict__ b1,
    const float* __restrict__ w2, const float* __restrict__ b2,
    const float* __restrict__ w3, const float* __restrict__ b3,
    float* __restrict__ xout) {
  const int bm = blockIdx.x;      // b*2048 + m
  const int b  = bm >> 11;
  const int j  = threadIdx.x;     // lane = neighbor row
  __shared__ float s_h[64 * 65];  // stride 65: conflict-free own-row access
  const int cnt = ncnt[bm];
  float* outp = xout + (size_t)bm * 128;
  if (cnt == 0) { outp[j] = 0.f; outp[j + 64] = 0.f; return; }
  const float qx = posq[(size_t)bm*3+0], qy = posq[(size_t)bm*3+1], qz = posq[(size_t)bm*3+2];
  const bool act = j < cnt;
  float rx = 0.f, ry = 0.f, rz = 0.f;
  if (act) {
    const int n = nidx[(size_t)bm*64 + j];
    const float* p = pos + ((size_t)b*4096 + n) * 3;
    rx = p[0] - qx; ry = p[1] - qy; rz = p[2] - qz;
  }
  // L1: 3->64 + relu
#pragma unroll
  for (int c = 0; c < 64; ++c) {
    const float a = b1[c] + rx * w1[c] + ry * w1[64 + c] + rz * w1[128 + c];
    s_h[j*65 + c] = fmaxf(a, 0.f);
  }
  __syncthreads();
  // L2: 64->64 + relu (weights wave-uniform -> scalar loads)
  float acc[64];
#pragma unroll
  for (int c = 0; c < 64; ++c) acc[c] = b2[c];
#pragma unroll 1
  for (int k = 0; k < 64; ++k) {
    const float hk = s_h[j*65 + k];
#pragma unroll
    for (int c4 = 0; c4 < 16; ++c4) {
      const float4 w = *(const float4*)(w2 + k*64 + c4*4);
      acc[c4*4+0] += hk * w.x; acc[c4*4+1] += hk * w.y;
      acc[c4*4+2] += hk * w.z; acc[c4*4+3] += hk * w.w;
    }
  }
  __syncthreads();
#pragma unroll
  for (int c = 0; c < 64; ++c) s_h[j*65 + c] = fmaxf(acc[c], 0.f);
  __syncthreads();
  // L3: 64->128 + masked col-max over rows + outer relu
#pragma unroll 1
  for (int ch = 0; ch < 2; ++ch) {
    float a3[64];
#pragma unroll
    for (int c = 0; c < 64; ++c) a3[c] = b3[ch*64 + c];
#pragma unroll 1
    for (int k = 0; k < 64; ++k) {
      const float hk = s_h[j*65 + k];
#pragma unroll
      for (int c4 = 0; c4 < 16; ++c4) {
        const float4 w = *(const float4*)(w3 + k*128 + ch*64 + c4*4);
        a3[c4*4+0] += hk * w.x; a3[c4*4+1] += hk * w.y;
        a3[c4*4+2] += hk * w.z; a3[c4*4+3] += hk * w.w;
      }
    }
    float res = 0.f;
#pragma unroll
    for (int c = 0; c < 64; ++c) {
      float v = act ? a3[c] : -1e30f;   // matches ref NEG masking
#pragma unroll
      for (int off = 32; off > 0; off >>= 1) v = fmaxf(v, __shfl_xor(v, off, 64));
      if (j == c) res = v;
    }
    outp[ch*64 + j] = fmaxf(res, 0.f);
  }
}

// --- conv2: msg=[x1_j(128), rel(3)] -> 128 -> 128 -> 256, masked max, relu --
__global__ __launch_bounds__(64) void conv2_kernel(
    const float* __restrict__ x1, const float* __restrict__ pos1, const float* __restrict__ pos2,
    const int* __restrict__ nidx, const int* __restrict__ ncnt,
    const float* __restrict__ w1, const float* __restrict__ b1,
    const float* __restrict__ w2, const float* __restrict__ b2,
    const float* __restrict__ w3, const float* __restrict__ b3,
    float* __restrict__ xout) {
  const int bm = blockIdx.x;      // b*512 + m
  const int b  = bm >> 9;
  const int j  = threadIdx.x;
  __shared__ float s_h[64 * 128]; // XOR-swizzled rows (conflict-free col reads)
  const int cnt = ncnt[bm];
  float* outp = xout + (size_t)bm * 256;
  if (cnt == 0) {
#pragma unroll
    for (int c = 0; c < 4; ++c) outp[c*64 + j] = 0.f;
    return;
  }
  const float qx = pos2[(size_t)bm*3+0], qy = pos2[(size_t)bm*3+1], qz = pos2[(size_t)bm*3+2];
  const bool act = j < cnt;
  int n = 0;
  float rx = 0.f, ry = 0.f, rz = 0.f;
  if (act) {
    n = nidx[(size_t)bm*64 + j];
    const float* p = pos1 + ((size_t)b*2048 + n) * 3;
    rx = p[0] - qx; ry = p[1] - qy; rz = p[2] - qz;
  }
  const float* xj = x1 + ((size_t)b*2048 + n) * 128;  // n=0 for idle lanes: finite garbage, masked later
  const int sw = (j & 31);
  float acc[128];
#pragma unroll
  for (int c = 0; c < 128; ++c) acc[c] = b1[c];
  auto fmarow1 = [&](int krow, float xk) {
#pragma unroll
    for (int c4 = 0; c4 < 32; ++c4) {
      const float4 w = *(const float4*)(w1 + krow*128 + c4*4);
      acc[c4*4+0] += xk*w.x; acc[c4*4+1] += xk*w.y;
      acc[c4*4+2] += xk*w.z; acc[c4*4+3] += xk*w.w;
    }
  };
#pragma unroll 1
  for (int k = 0; k < 128; k += 4) {
    const float4 xv = *(const float4*)(xj + k);
    fmarow1(k+0, xv.x); fmarow1(k+1, xv.y); fmarow1(k+2, xv.z); fmarow1(k+3, xv.w);
  }
  fmarow1(128, rx); fmarow1(129, ry); fmarow1(130, rz);
#pragma unroll
  for (int c = 0; c < 128; ++c) s_h[j*128 + (c ^ sw)] = fmaxf(acc[c], 0.f);
  __syncthreads();
  // L2: 128->128 + relu
  float a2[128];
#pragma unroll
  for (int c = 0; c < 128; ++c) a2[c] = b2[c];
#pragma unroll 1
  for (int k = 0; k < 128; ++k) {
    const float hk = s_h[j*128 + (k ^ sw)];
#pragma unroll
    for (int c4 = 0; c4 < 32; ++c4) {
      const float4 w = *(const float4*)(w2 + k*128 + c4*4);
      a2[c4*4+0] += hk*w.x; a2[c4*4+1] += hk*w.y;
      a2[c4*4+2] += hk*w.z; a2[c4*4+3] += hk*w.w;
    }
  }
  __syncthreads();
#pragma unroll
  for (int c = 0; c < 128; ++c) s_h[j*128 + (c ^ sw)] = fmaxf(a2[c], 0.f);
  __syncthreads();
  // L3: 128->256 + masked col-max + relu
#pragma unroll 1
  for (int ch = 0; ch < 4; ++ch) {
    float a3[64];
#pragma unroll
    for (int c = 0; c < 64; ++c) a3[c] = b3[ch*64 + c];
#pragma unroll 1
    for (int k = 0; k < 128; ++k) {
      const float hk = s_h[j*128 + (k ^ sw)];
#pragma unroll
      for (int c4 = 0; c4 < 16; ++c4) {
        const float4 w = *(const float4*)(w3 + k*256 + ch*64 + c4*4);
        a3[c4*4+0] += hk*w.x; a3[c4*4+1] += hk*w.y;
        a3[c4*4+2] += hk*w.z; a3[c4*4+3] += hk*w.w;
      }
    }
    float res = 0.f;
#pragma unroll
    for (int c = 0; c < 64; ++c) {
      float v = act ? a3[c] : -1e30f;
#pragma unroll
      for (int off = 32; off > 0; off >>= 1) v = fmaxf(v, __shfl_xor(v, off, 64));
      if (j == c) res = v;
    }
    outp[ch*64 + j] = fmaxf(res, 0.f);
  }
}

// --------- global MLP 259->256->512->1024, per-block(16pt) partial max ------
__global__ __launch_bounds__(256) void gmlp_kernel(
    const float* __restrict__ x2, const float* __restrict__ pos2,
    const float* __restrict__ w1, const float* __restrict__ b1,
    const float* __restrict__ w2, const float* __restrict__ b2,
    const float* __restrict__ w3, const float* __restrict__ b3,
    float* __restrict__ gpart) {
  const int blk = blockIdx.x;     // 16 points per block (group = 8 blocks)
  const int t = threadIdx.x;
  __shared__ float sA[16 * 260];  // input, reused for H1
  __shared__ float sB[16 * 512];  // H2
  const int p0 = blk * 16;
  for (int i = t; i < 16*256; i += 256) {
    const int p = i >> 8, k = i & 255;
    sA[p*260 + k] = x2[(size_t)(p0 + p)*256 + k];
  }
  if (t < 48) { const int p = t/3, c = t%3; sA[p*260 + 256 + c] = pos2[(size_t)(p0+p)*3 + c]; }
  __syncthreads();
  float h1[16];
#pragma unroll
  for (int p = 0; p < 16; ++p) h1[p] = b1[t];
#pragma unroll 1
  for (int k = 0; k < 259; ++k) {
    const float w = w1[(size_t)k*256 + t];
#pragma unroll
    for (int p = 0; p < 16; ++p) h1[p] += sA[p*260 + k] * w;
  }
  __syncthreads();
#pragma unroll
  for (int p = 0; p < 16; ++p) sA[p*260 + t] = fmaxf(h1[p], 0.f);
  __syncthreads();
  float h2a[16], h2b[16];
#pragma unroll
  for (int p = 0; p < 16; ++p) { h2a[p] = b2[t]; h2b[p] = b2[t + 256]; }
#pragma unroll 1
  for (int k = 0; k < 256; ++k) {
    const float wa = w2[(size_t)k*512 + t];
    const float wb = w2[(size_t)k*512 + t + 256];
#pragma unroll
    for (int p = 0; p < 16; ++p) { const float x = sA[p*260 + k]; h2a[p] += x*wa; h2b[p] += x*wb; }
  }
#pragma unroll
  for (int p = 0; p < 16; ++p) { sB[p*512 + t] = fmaxf(h2a[p], 0.f); sB[p*512 + t + 256] = fmaxf(h2b[p], 0.f); }
  __syncthreads();
  float a3[4][16];
#pragma unroll
  for (int c = 0; c < 4; ++c) {
    const float bb = b3[t + c*256];
#pragma unroll
    for (int p = 0; p < 16; ++p) a3[c][p] = bb;
  }
#pragma unroll 1
  for (int k = 0; k < 512; ++k) {
    float hk[16];
#pragma unroll
    for (int p = 0; p < 16; ++p) hk[p] = sB[p*512 + k];
#pragma unroll
    for (int c = 0; c < 4; ++c) {
      const float w = w3[(size_t)k*1024 + t + c*256];
#pragma unroll
      for (int p = 0; p < 16; ++p) a3[c][p] += hk[p] * w;
    }
  }
#pragma unroll
  for (int c = 0; c < 4; ++c) {
    float m = a3[c][0];
#pragma unroll
    for (int p = 1; p < 16; ++p) m = fmaxf(m, a3[c][p]);
    gpart[(size_t)blk*1024 + t + c*256] = m;
  }
}

__global__ __launch_bounds__(256) void gmax_kernel(const float* __restrict__ gpart,
                                                   float* __restrict__ gmaxb) {
  const int g = blockIdx.x >> 2, chunk = blockIdx.x & 3;
  const int ch = chunk*256 + threadIdx.x;
  float v = gpart[(size_t)(g*8)*1024 + ch];
#pragma unroll
  for (int r = 1; r < 8; ++r) v = fmaxf(v, gpart[(size_t)(g*8 + r)*1024 + ch]);
  gmaxb[(size_t)g*1024 + ch] = v;
}

// ---------------- head MLP 1024->512->256->7 per group-row ------------------
__global__ __launch_bounds__(256) void head_kernel(
    const float* __restrict__ gin,
    const float* __restrict__ l1w, const float* __restrict__ l1b,
    const float* __restrict__ l2w, const float* __restrict__ l2b,
    const float* __restrict__ l3w, const float* __restrict__ l3b,
    float* __restrict__ h3) {
  const int r = blockIdx.x, t = threadIdx.x;
  __shared__ float sIn[1024];
  __shared__ float sH[512];
  __shared__ float sH2[256];
  for (int i = t; i < 1024; i += 256) sIn[i] = gin[(size_t)r*1024 + i];
  __syncthreads();
  float a0 = l1b[t], a1 = l1b[t + 256];
#pragma unroll 1
  for (int k = 0; k < 1024; ++k) {
    const float x = sIn[k];
    a0 += x * l1w[(size_t)k*512 + t];
    a1 += x * l1w[(size_t)k*512 + t + 256];
  }
  sH[t] = fmaxf(a0, 0.f); sH[t+256] = fmaxf(a1, 0.f);
  __syncthreads();
  float a = l2b[t];
#pragma unroll 1
  for (int k = 0; k < 512; ++k) a += sH[k] * l2w[(size_t)k*256 + t];
  sH2[t] = fmaxf(a, 0.f);
  __syncthreads();
  if (t < 7) {
    float acc = l3b[t];
#pragma unroll 1
    for (int k = 0; k < 256; ++k) acc += sH2[k] * l3w[(size_t)k*7 + t];
    h3[(size_t)r*7 + t] = acc;
  }
}

// ---------------- mean over 4 group-rows + quaternion normalize -------------
__global__ void final_kernel(const float* __restrict__ h3, float* __restrict__ out) {
  const int b = threadIdx.x;
  if (b >= 8) return;
  float v[7];
#pragma unroll
  for (int c = 0; c < 7; ++c) {
    const float s = ((h3[(b*4+0)*7+c] + h3[(b*4+1)*7+c]) + h3[(b*4+2)*7+c]) + h3[(b*4+3)*7+c];
    v[c] = s * 0.25f;
  }
  const float nrm = fmaxf(sqrtf(((v[3]*v[3] + v[4]*v[4]) + v[5]*v[5]) + v[6]*v[6]), 1e-12f);
  out[b*7+0] = v[0]; out[b*7+1] = v[1]; out[b*7+2] = v[2];
  out[b*7+3] = v[3]/nrm; out[b*7+4] = v[4]/nrm;
  out[b*7+5] = v[5]/nrm; out[b*7+6] = v[6]/nrm;
}

extern "C" void kernel_launch(void* const* d_in, const int* in_sizes, int n_in,
                              void* d_out, int out_size, void* d_ws, size_t ws_size,
                              hipStream_t stream) {
  const float* points = (const float*)d_in[0];
  const float* sa1_w1 = (const float*)d_in[1];
  const float* sa1_b1 = (const float*)d_in[2];
  const float* sa1_w2 = (const float*)d_in[3];
  const float* sa1_b2 = (const float*)d_in[4];
  const float* sa1_w3 = (const float*)d_in[5];
  const float* sa1_b3 = (const float*)d_in[6];
  const float* sa2_w1 = (const float*)d_in[7];
  const float* sa2_b1 = (const float*)d_in[8];
  const float* sa2_w2 = (const float*)d_in[9];
  const float* sa2_b2 = (const float*)d_in[10];
  const float* sa2_w3 = (const float*)d_in[11];
  const float* sa2_b3 = (const float*)d_in[12];
  const float* g_w1   = (const float*)d_in[13];
  const float* g_b1   = (const float*)d_in[14];
  const float* g_w2   = (const float*)d_in[15];
  const float* g_b2   = (const float*)d_in[16];
  const float* g_w3   = (const float*)d_in[17];
  const float* g_b3   = (const float*)d_in[18];
  const float* l1_w   = (const float*)d_in[19];
  const float* l1_b   = (const float*)d_in[20];
  const float* l2_w   = (const float*)d_in[21];
  const float* l2_b   = (const float*)d_in[22];
  const float* l3_w   = (const float*)d_in[23];
  const float* l3_b   = (const float*)d_in[24];

  // Workspace carve-up (all 4-byte elements), ~19.3 MB total.
  float* ws = (float*)d_ws;
  size_t o = 0;
  float* pos1  = ws + o; o += (size_t)8*2048*3;
  float* pos2  = ws + o; o += (size_t)8*512*3;
  int*   nidx1 = (int*)(ws + o); o += (size_t)8*2048*64;
  int*   ncnt1 = (int*)(ws + o); o += (size_t)8*2048;
  int*   nidx2 = (int*)(ws + o); o += (size_t)8*512*64;
  int*   ncnt2 = (int*)(ws + o); o += (size_t)8*512;
  float* x1    = ws + o; o += (size_t)8*2048*128;
  float* x2    = ws + o; o += (size_t)8*512*256;
  float* gpart = ws + o; o += (size_t)256*1024;
  float* gmaxb = ws + o; o += (size_t)32*1024;
  float* h3    = ws + o; o += (size_t)32*7;

  // Radius thresholds: Python computes r*r in double, JAX weak-types to f32.
  const float R2_1 = (float)(0.1 * 0.1);
  const float R2_2 = (float)(0.2 * 0.2);

  fps_kernel<4096, 2048, 256><<<8, 256, 0, stream>>>(points, pos1);
  radius_kernel<1024><<<8*2048, 128, 0, stream>>>(points, pos1, 4096, 2048, R2_1, nidx1, ncnt1);
  conv1_kernel<<<8*2048, 64, 0, stream>>>(points, pos1, nidx1, ncnt1,
                                          sa1_w1, sa1_b1, sa1_w2, sa1_b2, sa1_w3, sa1_b3, x1);
  fps_kernel<2048, 512, 256><<<8, 256, 0, stream>>>(pos1, pos2);
  radius_kernel<1024><<<8*512, 128, 0, stream>>>(pos1, pos2, 2048, 512, R2_2, nidx2, ncnt2);
  conv2_kernel<<<8*512, 64, 0, stream>>>(x1, pos1, pos2, nidx2, ncnt2,
                                         sa2_w1, sa2_b1, sa2_w2, sa2_b2, sa2_w3, sa2_b3, x2);
  gmlp_kernel<<<256, 256, 0, stream>>>(x2, pos2, g_w1, g_b1, g_w2, g_b2, g_w3, g_b3, gpart);
  gmax_kernel<<<128, 256, 0, stream>>>(gpart, gmaxb);
  head_kernel<<<32, 256, 0, stream>>>(gmaxb, l1_w, l1_b, l2_w, l2_b, l3_w, l3_b, h3);
  final_kernel<<<1, 64, 0, stream>>>(h3, (float*)d_out);
}

// Round 3
// 3609.509 us; speedup vs baseline: 1.3935x; 1.1517x over previous
//
#include <hip/hip_runtime.h>
#include <float.h>

// CloudNet (PointNet++-ish) full pipeline on MI355X.
// Correctness contract: FPS + radius selection must be bit-exact vs numpy f32
// (no FMA contraction -> explicit __f*_rn ops; argmax/top_k tie-breaks by
// lowest index). MLP math is free to use pk-FMA (tolerance absorbs rounding).

typedef float f32x2 __attribute__((ext_vector_type(2)));

__device__ __forceinline__ float d2_rn(float ax, float ay, float az,
                                       float bx, float by, float bz) {
  float dx = __fsub_rn(ax, bx), dy = __fsub_rn(ay, by), dz = __fsub_rn(az, bz);
  return __fadd_rn(__fadd_rn(__fmul_rn(dx, dx), __fmul_rn(dy, dy)), __fmul_rn(dz, dz));
}

// u64 max step over a DPP lane pattern (LLVM AMDGPUAtomicOptimizer sequence).
template<int CTRL>
__device__ __forceinline__ unsigned long long dppmax(unsigned long long a) {
  const unsigned int lo = (unsigned int)a, hi = (unsigned int)(a >> 32);
  const unsigned int slo =
      (unsigned int)__builtin_amdgcn_update_dpp(0, (int)lo, CTRL, 0xf, 0xf, true);
  const unsigned int shi =
      (unsigned int)__builtin_amdgcn_update_dpp(0, (int)hi, CTRL, 0xf, 0xf, true);
  const unsigned long long s = ((unsigned long long)shi << 32) | slo;
  return s > a ? s : a;
}

// ---------------- FPS v3: DPP wave-reduce + float4 coord fetch --------------
// Key = (f32_bits(mind) << 32) | (N-1-idx): max-key == argmax with numpy's
// lowest-index tie-break (d2 >= 0 so float bits are order-isomorphic).
template<int N, int NS, int T>
__global__ __launch_bounds__(T) void fps_kernel(const float* __restrict__ pos,
                                                float* __restrict__ posq) {
  constexpr int P = N / T;
  constexpr int W = T / 64;
  __shared__ float4 s_xyz[N];
  __shared__ unsigned long long s_red[2][W];
  const int t = threadIdx.x, b = blockIdx.x;
  const float* pb = pos + (size_t)b * N * 3;
  for (int i = t; i < N; i += T)
    s_xyz[i] = make_float4(pb[i*3+0], pb[i*3+1], pb[i*3+2], 0.f);
  __syncthreads();
  float px[P], py[P], pz[P], mind[P];
  unsigned int kc[P];
#pragma unroll
  for (int j = 0; j < P; ++j) {
    const float4 c = s_xyz[j*T + t];
    px[j] = c.x; py[j] = c.y; pz[j] = c.z;
    mind[j] = FLT_MAX;                    // ref inits to finfo(f32).max
    kc[j] = (unsigned int)(N - 1 - (j*T + t));
  }
  float lx = s_xyz[0].x, ly = s_xyz[0].y, lz = s_xyz[0].z;  // start at point 0
  float* outp = posq + (size_t)b * NS * 3;
  if (t == 0) { outp[0] = lx; outp[1] = ly; outp[2] = lz; }
  for (int it = 1; it < NS; ++it) {
    float bv = -1.0f; unsigned int bk = 0;
#pragma unroll
    for (int j = 0; j < P; ++j) {
      const float dx = __fsub_rn(px[j], lx);
      const float dy = __fsub_rn(py[j], ly);
      const float dz = __fsub_rn(pz[j], lz);
      const float d = __fadd_rn(__fadd_rn(__fmul_rn(dx, dx), __fmul_rn(dy, dy)),
                                __fmul_rn(dz, dz));
      const float m = fminf(mind[j], d);
      mind[j] = m;
      const bool gt = m > bv;             // strict > => lowest j (= lowest idx) wins
      bv = gt ? m : bv;
      bk = gt ? kc[j] : bk;
    }
    unsigned long long key =
        ((unsigned long long)__float_as_uint(bv) << 32) | bk;
    key = dppmax<0x111>(key);  // row_shr:1
    key = dppmax<0x112>(key);  // row_shr:2
    key = dppmax<0x114>(key);  // row_shr:4
    key = dppmax<0x118>(key);  // row_shr:8
    key = dppmax<0x142>(key);  // row_bcast:15
    key = dppmax<0x143>(key);  // row_bcast:31
    const unsigned int wlo = (unsigned int)__builtin_amdgcn_readlane((int)(unsigned int)key, 63);
    const unsigned int whi = (unsigned int)__builtin_amdgcn_readlane((int)(unsigned int)(key >> 32), 63);
    unsigned long long best = ((unsigned long long)whi << 32) | wlo;
    if constexpr (W > 1) {
      const int par = it & 1;
      if ((t & 63) == 63) s_red[par][t >> 6] = best;
      __syncthreads();
#pragma unroll
      for (int w = 0; w < W; ++w) {
        const unsigned long long o = s_red[par][w];
        best = o > best ? o : best;
      }
    }
    const int idx = (N - 1) - (int)(unsigned int)(best & 0xFFFFFFFFull);
    const float4 c = s_xyz[idx];          // single b128 broadcast
    lx = c.x; ly = c.y; lz = c.z;
    if (t == 0) {                          // fire-and-forget
      outp[(size_t)it*3 + 0] = lx; outp[(size_t)it*3 + 1] = ly; outp[(size_t)it*3 + 2] = lz;
    }
  }
}

// ------------- radius-NN: one block per query, rank-select top-64 -----------
template<int CAP>
__global__ __launch_bounds__(128) void radius_kernel(
    const float* __restrict__ pall, const float* __restrict__ pq,
    int N, int M, float r2,
    int* __restrict__ nidx, int* __restrict__ ncnt) {
  const int bm = blockIdx.x;
  const int b = bm / M;
  const int t = threadIdx.x;
  __shared__ float s_d2[CAP];
  __shared__ int   s_id[CAP];
  __shared__ int   s_cnt;
  if (t == 0) s_cnt = 0;
  __syncthreads();
  const float* pb = pall + (size_t)b * N * 3;
  const float qx = pq[(size_t)bm*3], qy = pq[(size_t)bm*3+1], qz = pq[(size_t)bm*3+2];
  for (int i = t; i < N; i += 128) {
    const float d2 = d2_rn(qx, qy, qz, pb[i*3], pb[i*3+1], pb[i*3+2]);
    if (d2 <= r2) {
      const int p = atomicAdd(&s_cnt, 1);
      if (p < CAP) { s_d2[p] = d2; s_id[p] = i; }
    }
  }
  __syncthreads();
  const int cnt = min(s_cnt, CAP);
  int* out = nidx + (size_t)bm * 64;
  if (cnt <= 64) {
    if (t < cnt) out[t] = s_id[t];      // set equality suffices (max-agg)
    if (t == 0) ncnt[bm] = cnt;
  } else {
    // top_k(-d2): smallest d2, ties -> lower index. (d2,idx) lex rank < 64.
    for (int c = t; c < cnt; c += 128) {
      const float dc = s_d2[c]; const int ic = s_id[c];
      int rank = 0;
      for (int jj = 0; jj < cnt; ++jj)
        rank += (s_d2[jj] < dc) || (s_d2[jj] == dc && s_id[jj] < ic);
      if (rank < 64) out[rank] = s_id[c];
    }
    if (t == 0) ncnt[bm] = 64;
  }
}

// --------- conv1: msg=rel(3) -> 64 -> 64 -> 128, masked max, relu -----------
__global__ __launch_bounds__(64) void conv1_kernel(
    const float* __restrict__ pos, const float* __restrict__ posq,
    const int* __restrict__ nidx, const int* __restrict__ ncnt,
    const float* __restrict__ w1, const float* __restrict__ b1,
    const float* __restrict__ w2, const float* __restrict__ b2,
    const float* __restrict__ w3, const float* __restrict__ b3,
    float* __restrict__ xout) {
  const int bm = blockIdx.x;      // b*2048 + m
  const int b  = bm >> 11;
  const int j  = threadIdx.x;     // lane = neighbor row
  __shared__ float s_h[64 * 65];  // stride 65: conflict-free rows & columns
  const int cnt = ncnt[bm];
  float* outp = xout + (size_t)bm * 128;
  if (cnt == 0) { outp[j] = 0.f; outp[j + 64] = 0.f; return; }
  const float qx = posq[(size_t)bm*3+0], qy = posq[(size_t)bm*3+1], qz = posq[(size_t)bm*3+2];
  const bool act = j < cnt;
  float rx = 0.f, ry = 0.f, rz = 0.f;
  if (act) {
    const int n = nidx[(size_t)bm*64 + j];
    const float* p = pos + ((size_t)b*4096 + n) * 3;
    rx = p[0] - qx; ry = p[1] - qy; rz = p[2] - qz;
  }
  // L1: 3->64 + relu (pk math)
  {
    const f32x2 rx2 = {rx,rx}, ry2 = {ry,ry}, rz2 = {rz,rz};
    const f32x2* b1v = (const f32x2*)b1;
    const f32x2* w1a = (const f32x2*)(w1);
    const f32x2* w1b = (const f32x2*)(w1 + 64);
    const f32x2* w1c = (const f32x2*)(w1 + 128);
#pragma unroll
    for (int c = 0; c < 32; ++c) {
      f32x2 a = b1v[c] + rx2*w1a[c] + ry2*w1b[c] + rz2*w1c[c];
      a.x = fmaxf(a.x, 0.f); a.y = fmaxf(a.y, 0.f);
      *(f32x2*)(&s_h[j*65 + 2*c]) = a;
    }
  }
  __syncthreads();
  // L2: 64->64 + relu
  f32x2 acc[32];
  {
    const f32x2* b2v = (const f32x2*)b2;
#pragma unroll
    for (int c = 0; c < 32; ++c) acc[c] = b2v[c];
  }
#pragma unroll 2
  for (int k = 0; k < 64; ++k) {
    const float hk = s_h[j*65 + k];
    const f32x2 h2 = {hk, hk};
    const float4* wr = (const float4*)(w2 + k*64);
#pragma unroll
    for (int c4 = 0; c4 < 16; ++c4) {
      const float4 w = wr[c4];
      acc[c4*2+0] += h2 * f32x2{w.x, w.y};
      acc[c4*2+1] += h2 * f32x2{w.z, w.w};
    }
  }
  __syncthreads();
#pragma unroll
  for (int c = 0; c < 32; ++c) {
    f32x2 a = acc[c];
    a.x = fmaxf(a.x, 0.f); a.y = fmaxf(a.y, 0.f);
    *(f32x2*)(&s_h[j*65 + 2*c]) = a;
  }
  __syncthreads();
  // L3: 64->128, both output halves in one pass over s_h
  f32x2 a3[2][32];
  {
    const f32x2* b3v = (const f32x2*)b3;
#pragma unroll
    for (int ch = 0; ch < 2; ++ch)
#pragma unroll
      for (int c = 0; c < 32; ++c) a3[ch][c] = b3v[ch*32 + c];
  }
#pragma unroll 2
  for (int k = 0; k < 64; ++k) {
    const float hk = s_h[j*65 + k];
    const f32x2 h2 = {hk, hk};
    const float4* wr = (const float4*)(w3 + k*128);
#pragma unroll
    for (int ch = 0; ch < 2; ++ch)
#pragma unroll
      for (int c4 = 0; c4 < 16; ++c4) {
        const float4 w = wr[ch*16 + c4];
        a3[ch][c4*2+0] += h2 * f32x2{w.x, w.y};
        a3[ch][c4*2+1] += h2 * f32x2{w.z, w.w};
      }
  }
  // masked column-max via LDS transpose (s_h free now)
#pragma unroll 1
  for (int ch = 0; ch < 2; ++ch) {
    __syncthreads();
    if (act) {
#pragma unroll
      for (int c = 0; c < 32; ++c) *(f32x2*)(&s_h[j*65 + 2*c]) = a3[ch][c];
    } else {
      const f32x2 neg = {-1e30f, -1e30f};   // matches ref NEG masking
#pragma unroll
      for (int c = 0; c < 32; ++c) *(f32x2*)(&s_h[j*65 + 2*c]) = neg;
    }
    __syncthreads();
    float m = -1e30f;
#pragma unroll
    for (int r = 0; r < 64; ++r) m = fmaxf(m, s_h[r*65 + j]);
    outp[ch*64 + j] = fmaxf(m, 0.f);
  }
}

// --- conv2: msg=[x1_j(128), rel(3)] -> 128 -> 128 -> 256, masked max, relu --
__global__ __launch_bounds__(64) void conv2_kernel(
    const float* __restrict__ x1, const float* __restrict__ pos1, const float* __restrict__ pos2,
    const int* __restrict__ nidx, const int* __restrict__ ncnt,
    const float* __restrict__ w1, const float* __restrict__ b1,
    const float* __restrict__ w2, const float* __restrict__ b2,
    const float* __restrict__ w3, const float* __restrict__ b3,
    float* __restrict__ xout) {
  const int bm = blockIdx.x;      // b*512 + m
  const int b  = bm >> 9;
  const int j  = threadIdx.x;
  __shared__ float s_h[64 * 128]; // XOR-swizzled rows (conflict-free col reads)
  const int cnt = ncnt[bm];
  float* outp = xout + (size_t)bm * 256;
  if (cnt == 0) {
#pragma unroll
    for (int c = 0; c < 4; ++c) outp[c*64 + j] = 0.f;
    return;
  }
  const float qx = pos2[(size_t)bm*3+0], qy = pos2[(size_t)bm*3+1], qz = pos2[(size_t)bm*3+2];
  const bool act = j < cnt;
  int n = 0;
  float rx = 0.f, ry = 0.f, rz = 0.f;
  if (act) {
    n = nidx[(size_t)bm*64 + j];
    const float* p = pos1 + ((size_t)b*2048 + n) * 3;
    rx = p[0] - qx; ry = p[1] - qy; rz = p[2] - qz;
  }
  const float* xj = x1 + ((size_t)b*2048 + n) * 128;  // n=0 for idle lanes: finite garbage, masked later
  const int sw = (j & 31);
  f32x2 acc[64];
  {
    const f32x2* b1v = (const f32x2*)b1;
#pragma unroll
    for (int c = 0; c < 64; ++c) acc[c] = b1v[c];
  }
  auto fmarow1 = [&](int krow, float xk) {
    const f32x2 xv = {xk, xk};
    const float4* wr = (const float4*)(w1 + krow*128);
#pragma unroll
    for (int c4 = 0; c4 < 32; ++c4) {
      const float4 w = wr[c4];
      acc[c4*2+0] += xv * f32x2{w.x, w.y};
      acc[c4*2+1] += xv * f32x2{w.z, w.w};
    }
  };
#pragma unroll 2
  for (int k = 0; k < 128; k += 4) {
    const float4 xv = *(const float4*)(xj + k);
    fmarow1(k+0, xv.x); fmarow1(k+1, xv.y); fmarow1(k+2, xv.z); fmarow1(k+3, xv.w);
  }
  fmarow1(128, rx); fmarow1(129, ry); fmarow1(130, rz);
#pragma unroll
  for (int c = 0; c < 64; ++c) {
    const f32x2 a = acc[c];
    s_h[j*128 + ((2*c+0) ^ sw)] = fmaxf(a.x, 0.f);
    s_h[j*128 + ((2*c+1) ^ sw)] = fmaxf(a.y, 0.f);
  }
  __syncthreads();
  // L2: 128->128 + relu
  f32x2 a2[64];
  {
    const f32x2* b2v = (const f32x2*)b2;
#pragma unroll
    for (int c = 0; c < 64; ++c) a2[c] = b2v[c];
  }
#pragma unroll 2
  for (int k = 0; k < 128; ++k) {
    const float hk = s_h[j*128 + (k ^ sw)];
    const f32x2 h2 = {hk, hk};
    const float4* wr = (const float4*)(w2 + k*128);
#pragma unroll
    for (int c4 = 0; c4 < 32; ++c4) {
      const float4 w = wr[c4];
      a2[c4*2+0] += h2 * f32x2{w.x, w.y};
      a2[c4*2+1] += h2 * f32x2{w.z, w.w};
    }
  }
  __syncthreads();
#pragma unroll
  for (int c = 0; c < 64; ++c) {
    const f32x2 a = a2[c];
    s_h[j*128 + ((2*c+0) ^ sw)] = fmaxf(a.x, 0.f);
    s_h[j*128 + ((2*c+1) ^ sw)] = fmaxf(a.y, 0.f);
  }
  __syncthreads();
  // L3: 128->256 + masked col-max + relu
#pragma unroll 1
  for (int ch = 0; ch < 4; ++ch) {
    f32x2 a3[32];
    {
      const f32x2* b3v = (const f32x2*)(b3 + ch*64);
#pragma unroll
      for (int c = 0; c < 32; ++c) a3[c] = b3v[c];
    }
#pragma unroll 2
    for (int k = 0; k < 128; ++k) {
      const float hk = s_h[j*128 + (k ^ sw)];
      const f32x2 h2 = {hk, hk};
      const float4* wr = (const float4*)(w3 + k*256 + ch*64);
#pragma unroll
      for (int c4 = 0; c4 < 16; ++c4) {
        const float4 w = wr[c4];
        a3[c4*2+0] += h2 * f32x2{w.x, w.y};
        a3[c4*2+1] += h2 * f32x2{w.z, w.w};
      }
    }
    float res = 0.f;
#pragma unroll
    for (int c = 0; c < 64; ++c) {
      float v = act ? ((c & 1) ? a3[c>>1].y : a3[c>>1].x) : -1e30f;
#pragma unroll
      for (int off = 32; off > 0; off >>= 1) v = fmaxf(v, __shfl_xor(v, off, 64));
      if (j == c) res = v;
    }
    outp[ch*64 + j] = fmaxf(res, 0.f);
  }
}

// --------- global MLP 259->256->512->1024, per-block(16pt) partial max ------
__global__ __launch_bounds__(256) void gmlp_kernel(
    const float* __restrict__ x2, const float* __restrict__ pos2,
    const float* __restrict__ w1, const float* __restrict__ b1,
    const float* __restrict__ w2, const float* __restrict__ b2,
    const float* __restrict__ w3, const float* __restrict__ b3,
    float* __restrict__ gpart) {
  const int blk = blockIdx.x;     // 16 points per block (group = 8 blocks)
  const int t = threadIdx.x;
  __shared__ float sA[260 * 18];  // [k][p], pad 18 for 8B alignment
  __shared__ float sB[512 * 18];
  const int p0 = blk * 16;
  for (int i = t; i < 16*256; i += 256) {
    const int p = i >> 8, k = i & 255;
    sA[k*18 + p] = x2[(size_t)(p0 + p)*256 + k];
  }
  if (t < 48) { const int p = t/3, c = t%3; sA[(256+c)*18 + p] = pos2[(size_t)(p0+p)*3 + c]; }
  __syncthreads();
  f32x2 h1[8];
  { const float bb = b1[t];
#pragma unroll
    for (int p8 = 0; p8 < 8; ++p8) h1[p8] = f32x2{bb, bb}; }
#pragma unroll 2
  for (int k = 0; k < 259; ++k) {
    const float w = w1[(size_t)k*256 + t];
    const f32x2 wv = {w, w};
    const f32x2* row = (const f32x2*)(&sA[k*18]);
#pragma unroll
    for (int p8 = 0; p8 < 8; ++p8) h1[p8] += row[p8] * wv;
  }
  __syncthreads();
#pragma unroll
  for (int p8 = 0; p8 < 8; ++p8) {
    f32x2 a = h1[p8];
    a.x = fmaxf(a.x, 0.f); a.y = fmaxf(a.y, 0.f);
    *(f32x2*)(&sA[t*18 + 2*p8]) = a;
  }
  __syncthreads();
  f32x2 h2a[8], h2b[8];
  { const float ba = b2[t], bb = b2[t + 256];
#pragma unroll
    for (int p8 = 0; p8 < 8; ++p8) { h2a[p8] = f32x2{ba, ba}; h2b[p8] = f32x2{bb, bb}; } }
#pragma unroll 2
  for (int k = 0; k < 256; ++k) {
    const float wa = w2[(size_t)k*512 + t];
    const float wb = w2[(size_t)k*512 + t + 256];
    const f32x2 wav = {wa, wa}, wbv = {wb, wb};
    const f32x2* row = (const f32x2*)(&sA[k*18]);
#pragma unroll
    for (int p8 = 0; p8 < 8; ++p8) { const f32x2 x = row[p8]; h2a[p8] += x*wav; h2b[p8] += x*wbv; }
  }
  __syncthreads();
#pragma unroll
  for (int p8 = 0; p8 < 8; ++p8) {
    f32x2 a = h2a[p8], c = h2b[p8];
    a.x = fmaxf(a.x, 0.f); a.y = fmaxf(a.y, 0.f);
    c.x = fmaxf(c.x, 0.f); c.y = fmaxf(c.y, 0.f);
    *(f32x2*)(&sB[t*18 + 2*p8]) = a;
    *(f32x2*)(&sB[(t+256)*18 + 2*p8]) = c;
  }
  __syncthreads();
  f32x2 a3[4][8];
#pragma unroll
  for (int c = 0; c < 4; ++c) {
    const float bb = b3[t + c*256];
#pragma unroll
    for (int p8 = 0; p8 < 8; ++p8) a3[c][p8] = f32x2{bb, bb};
  }
#pragma unroll 2
  for (int k = 0; k < 512; ++k) {
    const f32x2* row = (const f32x2*)(&sB[k*18]);
    f32x2 xk[8];
#pragma unroll
    for (int p8 = 0; p8 < 8; ++p8) xk[p8] = row[p8];
#pragma unroll
    for (int c = 0; c < 4; ++c) {
      const float w = w3[(size_t)k*1024 + t + c*256];
      const f32x2 wv = {w, w};
#pragma unroll
      for (int p8 = 0; p8 < 8; ++p8) a3[c][p8] += xk[p8] * wv;
    }
  }
#pragma unroll
  for (int c = 0; c < 4; ++c) {
    f32x2 m2 = a3[c][0];
#pragma unroll
    for (int p8 = 1; p8 < 8; ++p8) {
      m2.x = fmaxf(m2.x, a3[c][p8].x); m2.y = fmaxf(m2.y, a3[c][p8].y);
    }
    gpart[(size_t)blk*1024 + t + c*256] = fmaxf(m2.x, m2.y);
  }
}

__global__ __launch_bounds__(256) void gmax_kernel(const float* __restrict__ gpart,
                                                   float* __restrict__ gmaxb) {
  const int g = blockIdx.x >> 2, chunk = blockIdx.x & 3;
  const int ch = chunk*256 + threadIdx.x;
  float v = gpart[(size_t)(g*8)*1024 + ch];
#pragma unroll
  for (int r = 1; r < 8; ++r) v = fmaxf(v, gpart[(size_t)(g*8 + r)*1024 + ch]);
  gmaxb[(size_t)g*1024 + ch] = v;
}

// ---------------- head MLP 1024->512->256->7 per group-row ------------------
__global__ __launch_bounds__(256) void head_kernel(
    const float* __restrict__ gin,
    const float* __restrict__ l1w, const float* __restrict__ l1b,
    const float* __restrict__ l2w, const float* __restrict__ l2b,
    const float* __restrict__ l3w, const float* __restrict__ l3b,
    float* __restrict__ h3) {
  const int r = blockIdx.x, t = threadIdx.x;
  __shared__ float sIn[1024];
  __shared__ float sH[512];
  __shared__ float sH2[256];
  for (int i = t; i < 1024; i += 256) sIn[i] = gin[(size_t)r*1024 + i];
  __syncthreads();
  float a0 = l1b[t], a1 = l1b[t + 256];
#pragma unroll 4
  for (int k = 0; k < 1024; ++k) {
    const float x = sIn[k];
    a0 += x * l1w[(size_t)k*512 + t];
    a1 += x * l1w[(size_t)k*512 + t + 256];
  }
  sH[t] = fmaxf(a0, 0.f); sH[t+256] = fmaxf(a1, 0.f);
  __syncthreads();
  float a = l2b[t];
#pragma unroll 4
  for (int k = 0; k < 512; ++k) a += sH[k] * l2w[(size_t)k*256 + t];
  sH2[t] = fmaxf(a, 0.f);
  __syncthreads();
  if (t < 7) {
    float acc = l3b[t];
#pragma unroll 4
    for (int k = 0; k < 256; ++k) acc += sH2[k] * l3w[(size_t)k*7 + t];
    h3[(size_t)r*7 + t] = acc;
  }
}

// ---------------- mean over 4 group-rows + quaternion normalize -------------
__global__ void final_kernel(const float* __restrict__ h3, float* __restrict__ out) {
  const int b = threadIdx.x;
  if (b >= 8) return;
  float v[7];
#pragma unroll
  for (int c = 0; c < 7; ++c) {
    const float s = ((h3[(b*4+0)*7+c] + h3[(b*4+1)*7+c]) + h3[(b*4+2)*7+c]) + h3[(b*4+3)*7+c];
    v[c] = s * 0.25f;
  }
  const float nrm = fmaxf(sqrtf(((v[3]*v[3] + v[4]*v[4]) + v[5]*v[5]) + v[6]*v[6]), 1e-12f);
  out[b*7+0] = v[0]; out[b*7+1] = v[1]; out[b*7+2] = v[2];
  out[b*7+3] = v[3]/nrm; out[b*7+4] = v[4]/nrm;
  out[b*7+5] = v[5]/nrm; out[b*7+6] = v[6]/nrm;
}

extern "C" void kernel_launch(void* const* d_in, const int* in_sizes, int n_in,
                              void* d_out, int out_size, void* d_ws, size_t ws_size,
                              hipStream_t stream) {
  const float* points = (const float*)d_in[0];
  const float* sa1_w1 = (const float*)d_in[1];
  const float* sa1_b1 = (const float*)d_in[2];
  const float* sa1_w2 = (const float*)d_in[3];
  const float* sa1_b2 = (const float*)d_in[4];
  const float* sa1_w3 = (const float*)d_in[5];
  const float* sa1_b3 = (const float*)d_in[6];
  const float* sa2_w1 = (const float*)d_in[7];
  const float* sa2_b1 = (const float*)d_in[8];
  const float* sa2_w2 = (const float*)d_in[9];
  const float* sa2_b2 = (const float*)d_in[10];
  const float* sa2_w3 = (const float*)d_in[11];
  const float* sa2_b3 = (const float*)d_in[12];
  const float* g_w1   = (const float*)d_in[13];
  const float* g_b1   = (const float*)d_in[14];
  const float* g_w2   = (const float*)d_in[15];
  const float* g_b2   = (const float*)d_in[16];
  const float* g_w3   = (const float*)d_in[17];
  const float* g_b3   = (const float*)d_in[18];
  const float* l1_w   = (const float*)d_in[19];
  const float* l1_b   = (const float*)d_in[20];
  const float* l2_w   = (const float*)d_in[21];
  const float* l2_b   = (const float*)d_in[22];
  const float* l3_w   = (const float*)d_in[23];
  const float* l3_b   = (const float*)d_in[24];

  // Workspace carve-up (all 4-byte elements), ~19.3 MB total.
  float* ws = (float*)d_ws;
  size_t o = 0;
  float* pos1  = ws + o; o += (size_t)8*2048*3;
  float* pos2  = ws + o; o += (size_t)8*512*3;
  int*   nidx1 = (int*)(ws + o); o += (size_t)8*2048*64;
  int*   ncnt1 = (int*)(ws + o); o += (size_t)8*2048;
  int*   nidx2 = (int*)(ws + o); o += (size_t)8*512*64;
  int*   ncnt2 = (int*)(ws + o); o += (size_t)8*512;
  float* x1    = ws + o; o += (size_t)8*2048*128;
  float* x2    = ws + o; o += (size_t)8*512*256;
  float* gpart = ws + o; o += (size_t)256*1024;
  float* gmaxb = ws + o; o += (size_t)32*1024;
  float* h3    = ws + o; o += (size_t)32*7;

  // Radius thresholds: Python computes r*r in double, JAX weak-types to f32.
  const float R2_1 = (float)(0.1 * 0.1);
  const float R2_2 = (float)(0.2 * 0.2);

  fps_kernel<4096, 2048, 256><<<8, 256, 0, stream>>>(points, pos1);
  radius_kernel<1024><<<8*2048, 128, 0, stream>>>(points, pos1, 4096, 2048, R2_1, nidx1, ncnt1);
  conv1_kernel<<<8*2048, 64, 0, stream>>>(points, pos1, nidx1, ncnt1,
                                          sa1_w1, sa1_b1, sa1_w2, sa1_b2, sa1_w3, sa1_b3, x1);
  fps_kernel<2048, 512, 256><<<8, 256, 0, stream>>>(pos1, pos2);
  radius_kernel<1024><<<8*512, 128, 0, stream>>>(pos1, pos2, 2048, 512, R2_2, nidx2, ncnt2);
  conv2_kernel<<<8*512, 64, 0, stream>>>(x1, pos1, pos2, nidx2, ncnt2,
                                         sa2_w1, sa2_b1, sa2_w2, sa2_b2, sa2_w3, sa2_b3, x2);
  gmlp_kernel<<<256, 256, 0, stream>>>(x2, pos2, g_w1, g_b1, g_w2, g_b2, g_w3, g_b3, gpart);
  gmax_kernel<<<128, 256, 0, stream>>>(gpart, gmaxb);
  head_kernel<<<32, 256, 0, stream>>>(gmaxb, l1_w, l1_b, l2_w, l2_b, l3_w, l3_b, h3);
  final_kernel<<<1, 64, 0, stream>>>(h3, (float*)d_out);
}

// Round 4
// 2721.290 us; speedup vs baseline: 1.8484x; 1.3264x over previous
//
#include <hip/hip_runtime.h>
#include <float.h>

// CloudNet (PointNet++-ish) full pipeline on MI355X.
// Correctness contract: FPS + radius selection must be bit-exact vs numpy f32
// (no FMA contraction -> explicit __f*_rn ops; argmax/top_k tie-breaks by
// lowest index). MLP math is free to use pk-FMA (tolerance absorbs rounding).

typedef float f32x2 __attribute__((ext_vector_type(2)));

__device__ __forceinline__ float d2_rn(float ax, float ay, float az,
                                       float bx, float by, float bz) {
  float dx = __fsub_rn(ax, bx), dy = __fsub_rn(ay, by), dz = __fsub_rn(az, bz);
  return __fadd_rn(__fadd_rn(__fmul_rn(dx, dx), __fmul_rn(dy, dy)), __fmul_rn(dz, dz));
}

// u64 max step over a DPP lane pattern (LLVM AMDGPUAtomicOptimizer sequence).
template<int CTRL>
__device__ __forceinline__ unsigned long long dppmax(unsigned long long a) {
  const unsigned int lo = (unsigned int)a, hi = (unsigned int)(a >> 32);
  const unsigned int slo =
      (unsigned int)__builtin_amdgcn_update_dpp(0, (int)lo, CTRL, 0xf, 0xf, true);
  const unsigned int shi =
      (unsigned int)__builtin_amdgcn_update_dpp(0, (int)hi, CTRL, 0xf, 0xf, true);
  const unsigned long long s = ((unsigned long long)shi << 32) | slo;
  return s > a ? s : a;
}

// ---------------- FPS: DPP wave-reduce + float4 coord fetch -----------------
// Key = (f32_bits(mind) << 32) | (N-1-idx): max-key == argmax with numpy's
// lowest-index tie-break (d2 >= 0 so float bits are order-isomorphic).
template<int N, int NS, int T>
__global__ __launch_bounds__(T) void fps_kernel(const float* __restrict__ pos,
                                                float* __restrict__ posq) {
  constexpr int P = N / T;
  constexpr int W = T / 64;
  __shared__ float4 s_xyz[N];
  __shared__ unsigned long long s_red[2][W];
  const int t = threadIdx.x, b = blockIdx.x;
  const float* pb = pos + (size_t)b * N * 3;
  for (int i = t; i < N; i += T)
    s_xyz[i] = make_float4(pb[i*3+0], pb[i*3+1], pb[i*3+2], 0.f);
  __syncthreads();
  float px[P], py[P], pz[P], mind[P];
  unsigned int kc[P];
#pragma unroll
  for (int j = 0; j < P; ++j) {
    const float4 c = s_xyz[j*T + t];
    px[j] = c.x; py[j] = c.y; pz[j] = c.z;
    mind[j] = FLT_MAX;                    // ref inits to finfo(f32).max
    kc[j] = (unsigned int)(N - 1 - (j*T + t));
  }
  float lx = s_xyz[0].x, ly = s_xyz[0].y, lz = s_xyz[0].z;  // start at point 0
  float* outp = posq + (size_t)b * NS * 3;
  if (t == 0) { outp[0] = lx; outp[1] = ly; outp[2] = lz; }
  for (int it = 1; it < NS; ++it) {
    float bv = -1.0f; unsigned int bk = 0;
#pragma unroll
    for (int j = 0; j < P; ++j) {
      const float dx = __fsub_rn(px[j], lx);
      const float dy = __fsub_rn(py[j], ly);
      const float dz = __fsub_rn(pz[j], lz);
      const float d = __fadd_rn(__fadd_rn(__fmul_rn(dx, dx), __fmul_rn(dy, dy)),
                                __fmul_rn(dz, dz));
      const float m = fminf(mind[j], d);
      mind[j] = m;
      const bool gt = m > bv;             // strict > => lowest j (= lowest idx) wins
      bv = gt ? m : bv;
      bk = gt ? kc[j] : bk;
    }
    unsigned long long key =
        ((unsigned long long)__float_as_uint(bv) << 32) | bk;
    key = dppmax<0x111>(key);  // row_shr:1
    key = dppmax<0x112>(key);  // row_shr:2
    key = dppmax<0x114>(key);  // row_shr:4
    key = dppmax<0x118>(key);  // row_shr:8
    key = dppmax<0x142>(key);  // row_bcast:15
    key = dppmax<0x143>(key);  // row_bcast:31
    const unsigned int wlo = (unsigned int)__builtin_amdgcn_readlane((int)(unsigned int)key, 63);
    const unsigned int whi = (unsigned int)__builtin_amdgcn_readlane((int)(unsigned int)(key >> 32), 63);
    unsigned long long best = ((unsigned long long)whi << 32) | wlo;
    if constexpr (W > 1) {
      const int par = it & 1;
      if ((t & 63) == 63) s_red[par][t >> 6] = best;
      __syncthreads();
#pragma unroll
      for (int w = 0; w < W; ++w) {
        const unsigned long long o = s_red[par][w];
        best = o > best ? o : best;
      }
    }
    const int idx = (N - 1) - (int)(unsigned int)(best & 0xFFFFFFFFull);
    const float4 c = s_xyz[idx];          // single b128 broadcast
    lx = c.x; ly = c.y; lz = c.z;
    if (t == 0) {                          // fire-and-forget
      outp[(size_t)it*3 + 0] = lx; outp[(size_t)it*3 + 1] = ly; outp[(size_t)it*3 + 2] = lz;
    }
  }
}

// ------------- radius-NN: one block per query, rank-select top-64 -----------
template<int CAP>
__global__ __launch_bounds__(128) void radius_kernel(
    const float* __restrict__ pall, const float* __restrict__ pq,
    int N, int M, float r2,
    int* __restrict__ nidx, int* __restrict__ ncnt) {
  const int bm = blockIdx.x;
  const int b = bm / M;
  const int t = threadIdx.x;
  __shared__ float s_d2[CAP];
  __shared__ int   s_id[CAP];
  __shared__ int   s_cnt;
  if (t == 0) s_cnt = 0;
  __syncthreads();
  const float* pb = pall + (size_t)b * N * 3;
  const float qx = pq[(size_t)bm*3], qy = pq[(size_t)bm*3+1], qz = pq[(size_t)bm*3+2];
  for (int i = t; i < N; i += 128) {
    const float d2 = d2_rn(qx, qy, qz, pb[i*3], pb[i*3+1], pb[i*3+2]);
    if (d2 <= r2) {
      const int p = atomicAdd(&s_cnt, 1);
      if (p < CAP) { s_d2[p] = d2; s_id[p] = i; }
    }
  }
  __syncthreads();
  const int cnt = min(s_cnt, CAP);
  int* out = nidx + (size_t)bm * 64;
  if (cnt <= 64) {
    if (t < cnt) out[t] = s_id[t];      // set equality suffices (max-agg)
    if (t == 0) ncnt[bm] = cnt;
  } else {
    // top_k(-d2): smallest d2, ties -> lower index. (d2,idx) lex rank < 64.
    for (int c = t; c < cnt; c += 128) {
      const float dc = s_d2[c]; const int ic = s_id[c];
      int rank = 0;
      for (int jj = 0; jj < cnt; ++jj)
        rank += (s_d2[jj] < dc) || (s_d2[jj] == dc && s_id[jj] < ic);
      if (rank < 64) out[rank] = s_id[c];
    }
    if (t == 0) ncnt[bm] = 64;
  }
}

// --------- conv1: msg=rel(3) -> 64 -> 64 -> 128, masked max, relu -----------
// 2 waves per query: wave g owns a 32/64-channel slice; h shared in LDS.
__global__ __launch_bounds__(128, 4) void conv1_kernel(
    const float* __restrict__ pos, const float* __restrict__ posq,
    const int* __restrict__ nidx, const int* __restrict__ ncnt,
    const float* __restrict__ w1, const float* __restrict__ b1,
    const float* __restrict__ w2, const float* __restrict__ b2,
    const float* __restrict__ w3, const float* __restrict__ b3,
    float* __restrict__ xout) {
  const int bm = blockIdx.x;      // b*2048 + m
  const int b  = bm >> 11;
  const int t  = threadIdx.x;
  const int j  = t & 63;          // neighbor row
  const int g  = __builtin_amdgcn_readfirstlane(t >> 6);  // wave slice id
  __shared__ float s_x[64 * 64];  // h buffer, XOR-swizzled cols
  __shared__ float s_rel[64 * 4];
  __shared__ float s_out[128];
  const int cnt = ncnt[bm];
  float* outp = xout + (size_t)bm * 128;
  if (cnt == 0) { outp[t] = 0.f; return; }
  if (t < 64) {
    const int n = (t < cnt) ? nidx[(size_t)bm*64 + t] : 0;  // finite filler row
    const float* p = pos + ((size_t)(b << 12) + n) * 3;
    const float qx = posq[(size_t)bm*3+0], qy = posq[(size_t)bm*3+1], qz = posq[(size_t)bm*3+2];
    s_rel[t*4+0] = p[0] - qx; s_rel[t*4+1] = p[1] - qy; s_rel[t*4+2] = p[2] - qz;
  }
  __syncthreads();
  const int sw  = (j & 15) << 1;  // even XOR swizzle, keeps f32x2 pairs aligned
  const int row = j * 64;
  const float rx = s_rel[j*4+0], ry = s_rel[j*4+1], rz = s_rel[j*4+2];
  // L1: 3 -> 64 (our 32-ch slice)
  f32x2 acc[16];
  {
    const f32x2* bv = (const f32x2*)(b1 + g*32);
#pragma unroll
    for (int c = 0; c < 16; ++c) acc[c] = bv[c];
  }
#pragma unroll
  for (int kk = 0; kk < 3; ++kk) {
    const float xk = (kk == 0) ? rx : ((kk == 1) ? ry : rz);
    const f32x2 xv = {xk, xk};
    const float4* wr = (const float4*)(w1 + kk*64 + g*32);
#pragma unroll
    for (int c4 = 0; c4 < 8; ++c4) {
      const float4 w = wr[c4];
      acc[c4*2+0] += xv * f32x2{w.x, w.y};
      acc[c4*2+1] += xv * f32x2{w.z, w.w};
    }
  }
#pragma unroll
  for (int c = 0; c < 16; ++c) {
    f32x2 v = acc[c];
    v.x = fmaxf(v.x, 0.f); v.y = fmaxf(v.y, 0.f);
    *(f32x2*)(&s_x[row + ((g*32 + 2*c) ^ sw)]) = v;
  }
  __syncthreads();
  // L2: 64 -> 64 (our 32-ch slice)
  {
    const f32x2* bv = (const f32x2*)(b2 + g*32);
#pragma unroll
    for (int c = 0; c < 16; ++c) acc[c] = bv[c];
  }
#pragma unroll 2
  for (int k = 0; k < 64; ++k) {
    const float hk = s_x[row + (k ^ sw)];
    const f32x2 hv = {hk, hk};
    const float4* wr = (const float4*)(w2 + k*64 + g*32);
#pragma unroll
    for (int c4 = 0; c4 < 8; ++c4) {
      const float4 w = wr[c4];
      acc[c4*2+0] += hv * f32x2{w.x, w.y};
      acc[c4*2+1] += hv * f32x2{w.z, w.w};
    }
  }
  __syncthreads();  // all L2 reads of h1 done
#pragma unroll
  for (int c = 0; c < 16; ++c) {
    f32x2 v = acc[c];
    v.x = fmaxf(v.x, 0.f); v.y = fmaxf(v.y, 0.f);
    *(f32x2*)(&s_x[row + ((g*32 + 2*c) ^ sw)]) = v;
  }
  __syncthreads();
  // L3: 64 -> 128 (our 64-ch slice, 2 passes) + masked col-max butterfly
#pragma unroll 1
  for (int p = 0; p < 2; ++p) {
    f32x2 a[16];
    {
      const f32x2* bv = (const f32x2*)(b3 + g*64 + p*32);
#pragma unroll
      for (int c = 0; c < 16; ++c) a[c] = bv[c];
    }
#pragma unroll 2
    for (int k = 0; k < 64; ++k) {
      const float hk = s_x[row + (k ^ sw)];
      const f32x2 hv = {hk, hk};
      const float4* wr = (const float4*)(w3 + k*128 + g*64 + p*32);
#pragma unroll
      for (int c4 = 0; c4 < 8; ++c4) {
        const float4 w = wr[c4];
        a[c4*2+0] += hv * f32x2{w.x, w.y};
        a[c4*2+1] += hv * f32x2{w.z, w.w};
      }
    }
    if (j >= cnt) {
#pragma unroll
      for (int c = 0; c < 16; ++c) a[c] = f32x2{-1e30f, -1e30f};  // ref NEG
    }
#pragma unroll
    for (int off = 32; off > 0; off >>= 1) {
#pragma unroll
      for (int c = 0; c < 16; ++c) {
        a[c].x = fmaxf(a[c].x, __shfl_xor(a[c].x, off, 64));
        a[c].y = fmaxf(a[c].y, __shfl_xor(a[c].y, off, 64));
      }
    }
    if (j == 0) {
#pragma unroll
      for (int c = 0; c < 16; ++c) *(f32x2*)(&s_out[g*64 + p*32 + 2*c]) = a[c];
    }
  }
  __syncthreads();
  outp[t] = fmaxf(s_out[t], 0.f);
}

// --- conv2: msg=[x1_j(128), rel(3)] -> 128 -> 128 -> 256, masked max, relu --
// 4 waves per query: wave g owns a 32/64-channel slice; h shared in LDS.
__global__ __launch_bounds__(256, 4) void conv2_kernel(
    const float* __restrict__ x1, const float* __restrict__ pos1, const float* __restrict__ pos2,
    const int* __restrict__ nidx, const int* __restrict__ ncnt,
    const float* __restrict__ w1, const float* __restrict__ b1,
    const float* __restrict__ w2, const float* __restrict__ b2,
    const float* __restrict__ w3, const float* __restrict__ b3,
    float* __restrict__ xout) {
  const int bm = blockIdx.x;      // b*512 + m
  const int b  = bm >> 9;
  const int t  = threadIdx.x;
  const int j  = t & 63;          // neighbor row
  const int g  = __builtin_amdgcn_readfirstlane(t >> 6);  // wave slice id
  __shared__ float s_x[64 * 128]; // msg/h buffer, XOR-swizzled cols
  __shared__ float s_rel[64 * 4];
  __shared__ int   s_n[64];
  __shared__ float s_out[256];
  const int cnt = ncnt[bm];
  float* outp = xout + (size_t)bm * 256;
  if (cnt == 0) { outp[t] = 0.f; return; }
  if (t < 64) {
    const int n = (t < cnt) ? nidx[(size_t)bm*64 + t] : 0;  // finite filler row
    s_n[t] = n;
    const float* p = pos1 + ((size_t)(b << 11) + n) * 3;
    const float qx = pos2[(size_t)bm*3+0], qy = pos2[(size_t)bm*3+1], qz = pos2[(size_t)bm*3+2];
    s_rel[t*4+0] = p[0] - qx; s_rel[t*4+1] = p[1] - qy; s_rel[t*4+2] = p[2] - qz;
  }
  __syncthreads();
  // stage x1 rows (gather), swizzled
  for (int i = t; i < 64*128; i += 256) {
    const int r = i >> 7, c = i & 127;
    s_x[r*128 + (c ^ ((r & 15) << 1))] = x1[((size_t)(b << 11) + s_n[r])*128 + c];
  }
  __syncthreads();
  const int sw  = (j & 15) << 1;
  const int row = j * 128;
  // L1: 131 -> 128 (our 32-ch slice)
  f32x2 acc[16];
  {
    const f32x2* bv = (const f32x2*)(b1 + g*32);
#pragma unroll
    for (int c = 0; c < 16; ++c) acc[c] = bv[c];
  }
#pragma unroll 2
  for (int k = 0; k < 128; ++k) {
    const float xk = s_x[row + (k ^ sw)];
    const f32x2 xv = {xk, xk};
    const float4* wr = (const float4*)(w1 + k*128 + g*32);
#pragma unroll
    for (int c4 = 0; c4 < 8; ++c4) {
      const float4 w = wr[c4];
      acc[c4*2+0] += xv * f32x2{w.x, w.y};
      acc[c4*2+1] += xv * f32x2{w.z, w.w};
    }
  }
#pragma unroll
  for (int kk = 0; kk < 3; ++kk) {
    const float xk = s_rel[j*4 + kk];
    const f32x2 xv = {xk, xk};
    const float4* wr = (const float4*)(w1 + (128 + kk)*128 + g*32);
#pragma unroll
    for (int c4 = 0; c4 < 8; ++c4) {
      const float4 w = wr[c4];
      acc[c4*2+0] += xv * f32x2{w.x, w.y};
      acc[c4*2+1] += xv * f32x2{w.z, w.w};
    }
  }
  __syncthreads();  // all L1 reads of msg done
#pragma unroll
  for (int c = 0; c < 16; ++c) {
    f32x2 v = acc[c];
    v.x = fmaxf(v.x, 0.f); v.y = fmaxf(v.y, 0.f);
    *(f32x2*)(&s_x[row + ((g*32 + 2*c) ^ sw)]) = v;
  }
  __syncthreads();
  // L2: 128 -> 128 (our 32-ch slice)
  {
    const f32x2* bv = (const f32x2*)(b2 + g*32);
#pragma unroll
    for (int c = 0; c < 16; ++c) acc[c] = bv[c];
  }
#pragma unroll 2
  for (int k = 0; k < 128; ++k) {
    const float hk = s_x[row + (k ^ sw)];
    const f32x2 hv = {hk, hk};
    const float4* wr = (const float4*)(w2 + k*128 + g*32);
#pragma unroll
    for (int c4 = 0; c4 < 8; ++c4) {
      const float4 w = wr[c4];
      acc[c4*2+0] += hv * f32x2{w.x, w.y};
      acc[c4*2+1] += hv * f32x2{w.z, w.w};
    }
  }
  __syncthreads();  // all L2 reads of h1 done
#pragma unroll
  for (int c = 0; c < 16; ++c) {
    f32x2 v = acc[c];
    v.x = fmaxf(v.x, 0.f); v.y = fmaxf(v.y, 0.f);
    *(f32x2*)(&s_x[row + ((g*32 + 2*c) ^ sw)]) = v;
  }
  __syncthreads();
  // L3: 128 -> 256 (our 64-ch slice, 2 passes) + masked col-max butterfly
#pragma unroll 1
  for (int p = 0; p < 2; ++p) {
    f32x2 a[16];
    {
      const f32x2* bv = (const f32x2*)(b3 + g*64 + p*32);
#pragma unroll
      for (int c = 0; c < 16; ++c) a[c] = bv[c];
    }
#pragma unroll 2
    for (int k = 0; k < 128; ++k) {
      const float hk = s_x[row + (k ^ sw)];
      const f32x2 hv = {hk, hk};
      const float4* wr = (const float4*)(w3 + k*256 + g*64 + p*32);
#pragma unroll
      for (int c4 = 0; c4 < 8; ++c4) {
        const float4 w = wr[c4];
        a[c4*2+0] += hv * f32x2{w.x, w.y};
        a[c4*2+1] += hv * f32x2{w.z, w.w};
      }
    }
    if (j >= cnt) {
#pragma unroll
      for (int c = 0; c < 16; ++c) a[c] = f32x2{-1e30f, -1e30f};  // ref NEG
    }
#pragma unroll
    for (int off = 32; off > 0; off >>= 1) {
#pragma unroll
      for (int c = 0; c < 16; ++c) {
        a[c].x = fmaxf(a[c].x, __shfl_xor(a[c].x, off, 64));
        a[c].y = fmaxf(a[c].y, __shfl_xor(a[c].y, off, 64));
      }
    }
    if (j == 0) {
#pragma unroll
      for (int c = 0; c < 16; ++c) *(f32x2*)(&s_out[g*64 + p*32 + 2*c]) = a[c];
    }
  }
  __syncthreads();
  outp[t] = fmaxf(s_out[t], 0.f);
}

// --------- global MLP 259->256->512->1024, per-block(16pt) partial max ------
__global__ __launch_bounds__(256) void gmlp_kernel(
    const float* __restrict__ x2, const float* __restrict__ pos2,
    const float* __restrict__ w1, const float* __restrict__ b1,
    const float* __restrict__ w2, const float* __restrict__ b2,
    const float* __restrict__ w3, const float* __restrict__ b3,
    float* __restrict__ gpart) {
  const int blk = blockIdx.x;     // 16 points per block (group = 8 blocks)
  const int t = threadIdx.x;
  __shared__ float sA[260 * 18];  // [k][p], pad 18 for 8B alignment
  __shared__ float sB[512 * 18];
  const int p0 = blk * 16;
  for (int i = t; i < 16*256; i += 256) {
    const int p = i >> 8, k = i & 255;
    sA[k*18 + p] = x2[(size_t)(p0 + p)*256 + k];
  }
  if (t < 48) { const int p = t/3, c = t%3; sA[(256+c)*18 + p] = pos2[(size_t)(p0+p)*3 + c]; }
  __syncthreads();
  f32x2 h1[8];
  { const float bb = b1[t];
#pragma unroll
    for (int p8 = 0; p8 < 8; ++p8) h1[p8] = f32x2{bb, bb}; }
#pragma unroll 2
  for (int k = 0; k < 259; ++k) {
    const float w = w1[(size_t)k*256 + t];
    const f32x2 wv = {w, w};
    const f32x2* row = (const f32x2*)(&sA[k*18]);
#pragma unroll
    for (int p8 = 0; p8 < 8; ++p8) h1[p8] += row[p8] * wv;
  }
  __syncthreads();
#pragma unroll
  for (int p8 = 0; p8 < 8; ++p8) {
    f32x2 a = h1[p8];
    a.x = fmaxf(a.x, 0.f); a.y = fmaxf(a.y, 0.f);
    *(f32x2*)(&sA[t*18 + 2*p8]) = a;
  }
  __syncthreads();
  f32x2 h2a[8], h2b[8];
  { const float ba = b2[t], bb = b2[t + 256];
#pragma unroll
    for (int p8 = 0; p8 < 8; ++p8) { h2a[p8] = f32x2{ba, ba}; h2b[p8] = f32x2{bb, bb}; } }
#pragma unroll 2
  for (int k = 0; k < 256; ++k) {
    const float wa = w2[(size_t)k*512 + t];
    const float wb = w2[(size_t)k*512 + t + 256];
    const f32x2 wav = {wa, wa}, wbv = {wb, wb};
    const f32x2* row = (const f32x2*)(&sA[k*18]);
#pragma unroll
    for (int p8 = 0; p8 < 8; ++p8) { const f32x2 x = row[p8]; h2a[p8] += x*wav; h2b[p8] += x*wbv; }
  }
  __syncthreads();
#pragma unroll
  for (int p8 = 0; p8 < 8; ++p8) {
    f32x2 a = h2a[p8], c = h2b[p8];
    a.x = fmaxf(a.x, 0.f); a.y = fmaxf(a.y, 0.f);
    c.x = fmaxf(c.x, 0.f); c.y = fmaxf(c.y, 0.f);
    *(f32x2*)(&sB[t*18 + 2*p8]) = a;
    *(f32x2*)(&sB[(t+256)*18 + 2*p8]) = c;
  }
  __syncthreads();
  f32x2 a3[4][8];
#pragma unroll
  for (int c = 0; c < 4; ++c) {
    const float bb = b3[t + c*256];
#pragma unroll
    for (int p8 = 0; p8 < 8; ++p8) a3[c][p8] = f32x2{bb, bb};
  }
#pragma unroll 2
  for (int k = 0; k < 512; ++k) {
    const f32x2* row = (const f32x2*)(&sB[k*18]);
    f32x2 xk[8];
#pragma unroll
    for (int p8 = 0; p8 < 8; ++p8) xk[p8] = row[p8];
#pragma unroll
    for (int c = 0; c < 4; ++c) {
      const float w = w3[(size_t)k*1024 + t + c*256];
      const f32x2 wv = {w, w};
#pragma unroll
      for (int p8 = 0; p8 < 8; ++p8) a3[c][p8] += xk[p8] * wv;
    }
  }
#pragma unroll
  for (int c = 0; c < 4; ++c) {
    f32x2 m2 = a3[c][0];
#pragma unroll
    for (int p8 = 1; p8 < 8; ++p8) {
      m2.x = fmaxf(m2.x, a3[c][p8].x); m2.y = fmaxf(m2.y, a3[c][p8].y);
    }
    gpart[(size_t)blk*1024 + t + c*256] = fmaxf(m2.x, m2.y);
  }
}

__global__ __launch_bounds__(256) void gmax_kernel(const float* __restrict__ gpart,
                                                   float* __restrict__ gmaxb) {
  const int g = blockIdx.x >> 2, chunk = blockIdx.x & 3;
  const int ch = chunk*256 + threadIdx.x;
  float v = gpart[(size_t)(g*8)*1024 + ch];
#pragma unroll
  for (int r = 1; r < 8; ++r) v = fmaxf(v, gpart[(size_t)(g*8 + r)*1024 + ch]);
  gmaxb[(size_t)g*1024 + ch] = v;
}

// ---------------- head MLP 1024->512->256->7 per group-row ------------------
__global__ __launch_bounds__(256) void head_kernel(
    const float* __restrict__ gin,
    const float* __restrict__ l1w, const float* __restrict__ l1b,
    const float* __restrict__ l2w, const float* __restrict__ l2b,
    const float* __restrict__ l3w, const float* __restrict__ l3b,
    float* __restrict__ h3) {
  const int r = blockIdx.x, t = threadIdx.x;
  __shared__ float sIn[1024];
  __shared__ float sH[512];
  __shared__ float sH2[256];
  for (int i = t; i < 1024; i += 256) sIn[i] = gin[(size_t)r*1024 + i];
  __syncthreads();
  float a0 = l1b[t], a1 = l1b[t + 256];
#pragma unroll 4
  for (int k = 0; k < 1024; ++k) {
    const float x = sIn[k];
    a0 += x * l1w[(size_t)k*512 + t];
    a1 += x * l1w[(size_t)k*512 + t + 256];
  }
  sH[t] = fmaxf(a0, 0.f); sH[t+256] = fmaxf(a1, 0.f);
  __syncthreads();
  float a = l2b[t];
#pragma unroll 4
  for (int k = 0; k < 512; ++k) a += sH[k] * l2w[(size_t)k*256 + t];
  sH2[t] = fmaxf(a, 0.f);
  __syncthreads();
  if (t < 7) {
    float acc = l3b[t];
#pragma unroll 4
    for (int k = 0; k < 256; ++k) acc += sH2[k] * l3w[(size_t)k*7 + t];
    h3[(size_t)r*7 + t] = acc;
  }
}

// ---------------- mean over 4 group-rows + quaternion normalize -------------
__global__ void final_kernel(const float* __restrict__ h3, float* __restrict__ out) {
  const int b = threadIdx.x;
  if (b >= 8) return;
  float v[7];
#pragma unroll
  for (int c = 0; c < 7; ++c) {
    const float s = ((h3[(b*4+0)*7+c] + h3[(b*4+1)*7+c]) + h3[(b*4+2)*7+c]) + h3[(b*4+3)*7+c];
    v[c] = s * 0.25f;
  }
  const float nrm = fmaxf(sqrtf(((v[3]*v[3] + v[4]*v[4]) + v[5]*v[5]) + v[6]*v[6]), 1e-12f);
  out[b*7+0] = v[0]; out[b*7+1] = v[1]; out[b*7+2] = v[2];
  out[b*7+3] = v[3]/nrm; out[b*7+4] = v[4]/nrm;
  out[b*7+5] = v[5]/nrm; out[b*7+6] = v[6]/nrm;
}

extern "C" void kernel_launch(void* const* d_in, const int* in_sizes, int n_in,
                              void* d_out, int out_size, void* d_ws, size_t ws_size,
                              hipStream_t stream) {
  const float* points = (const float*)d_in[0];
  const float* sa1_w1 = (const float*)d_in[1];
  const float* sa1_b1 = (const float*)d_in[2];
  const float* sa1_w2 = (const float*)d_in[3];
  const float* sa1_b2 = (const float*)d_in[4];
  const float* sa1_w3 = (const float*)d_in[5];
  const float* sa1_b3 = (const float*)d_in[6];
  const float* sa2_w1 = (const float*)d_in[7];
  const float* sa2_b1 = (const float*)d_in[8];
  const float* sa2_w2 = (const float*)d_in[9];
  const float* sa2_b2 = (const float*)d_in[10];
  const float* sa2_w3 = (const float*)d_in[11];
  const float* sa2_b3 = (const float*)d_in[12];
  const float* g_w1   = (const float*)d_in[13];
  const float* g_b1   = (const float*)d_in[14];
  const float* g_w2   = (const float*)d_in[15];
  const float* g_b2   = (const float*)d_in[16];
  const float* g_w3   = (const float*)d_in[17];
  const float* g_b3   = (const float*)d_in[18];
  const float* l1_w   = (const float*)d_in[19];
  const float* l1_b   = (const float*)d_in[20];
  const float* l2_w   = (const float*)d_in[21];
  const float* l2_b   = (const float*)d_in[22];
  const float* l3_w   = (const float*)d_in[23];
  const float* l3_b   = (const float*)d_in[24];

  // Workspace carve-up (all 4-byte elements), ~19.3 MB total.
  float* ws = (float*)d_ws;
  size_t o = 0;
  float* pos1  = ws + o; o += (size_t)8*2048*3;
  float* pos2  = ws + o; o += (size_t)8*512*3;
  int*   nidx1 = (int*)(ws + o); o += (size_t)8*2048*64;
  int*   ncnt1 = (int*)(ws + o); o += (size_t)8*2048;
  int*   nidx2 = (int*)(ws + o); o += (size_t)8*512*64;
  int*   ncnt2 = (int*)(ws + o); o += (size_t)8*512;
  float* x1    = ws + o; o += (size_t)8*2048*128;
  float* x2    = ws + o; o += (size_t)8*512*256;
  float* gpart = ws + o; o += (size_t)256*1024;
  float* gmaxb = ws + o; o += (size_t)32*1024;
  float* h3    = ws + o; o += (size_t)32*7;

  // Radius thresholds: Python computes r*r in double, JAX weak-types to f32.
  const float R2_1 = (float)(0.1 * 0.1);
  const float R2_2 = (float)(0.2 * 0.2);

  fps_kernel<4096, 2048, 256><<<8, 256, 0, stream>>>(points, pos1);
  radius_kernel<1024><<<8*2048, 128, 0, stream>>>(points, pos1, 4096, 2048, R2_1, nidx1, ncnt1);
  conv1_kernel<<<8*2048, 128, 0, stream>>>(points, pos1, nidx1, ncnt1,
                                           sa1_w1, sa1_b1, sa1_w2, sa1_b2, sa1_w3, sa1_b3, x1);
  fps_kernel<2048, 512, 256><<<8, 256, 0, stream>>>(pos1, pos2);
  radius_kernel<1024><<<8*512, 128, 0, stream>>>(pos1, pos2, 2048, 512, R2_2, nidx2, ncnt2);
  conv2_kernel<<<8*512, 256, 0, stream>>>(x1, pos1, pos2, nidx2, ncnt2,
                                          sa2_w1, sa2_b1, sa2_w2, sa2_b2, sa2_w3, sa2_b3, x2);
  gmlp_kernel<<<256, 256, 0, stream>>>(x2, pos2, g_w1, g_b1, g_w2, g_b2, g_w3, g_b3, gpart);
  gmax_kernel<<<128, 256, 0, stream>>>(gpart, gmaxb);
  head_kernel<<<32, 256, 0, stream>>>(gmaxb, l1_w, l1_b, l2_w, l2_b, l3_w, l3_b, h3);
  final_kernel<<<1, 64, 0, stream>>>(h3, (float*)d_out);
}